// Round 1
// baseline (3807.955 us; speedup 1.0000x reference)
//
#include <hip/hip_runtime.h>
#include <math.h>

#define N_NODES 32768
#define N_FEAT 256
#define HID 256
#define N_GRAPHS 64
#define NPG 512
#define N_CLASSES 4
#define BN_EPS 1e-5f

// ---------------- degree ----------------
__global__ void k_init_deg(float* deg) {
    int i = blockIdx.x * 256 + threadIdx.x;
    if (i < N_NODES) deg[i] = 1.0f;
}

__global__ void k_count_deg(const int* __restrict__ dst, float* deg, int E) {
    int e = blockIdx.x * 256 + threadIdx.x;
    if (e < E) atomicAdd(&deg[dst[e]], 1.0f);
}

__global__ void k_dinv(const float* __restrict__ deg, float* __restrict__ dinv) {
    int i = blockIdx.x * 256 + threadIdx.x;
    if (i < N_NODES) dinv[i] = rsqrtf(deg[i]);
}

// ---------------- GEMM: C[M,256] = A[M,256] @ B[256,256], fp32 ----------------
__global__ __launch_bounds__(256) void k_gemm(const float* __restrict__ A,
                                              const float* __restrict__ B,
                                              float* __restrict__ C) {
    __shared__ float As[64][20];   // row stride 20 floats (80B, 16B-aligned)
    __shared__ float Bs[16][64];
    const int K = 256, N = 256;
    int tid = threadIdx.x;
    int bx = blockIdx.x;           // col tile 0..3
    int by = blockIdx.y;           // row tile 0..511
    int tx = tid & 15, ty = tid >> 4;

    float acc[4][4] = {};

    int a_r   = tid >> 2;          // 0..63
    int a_c4  = (tid & 3) * 4;     // 0,4,8,12
    int b_r   = tid >> 4;          // 0..15
    int b_c4  = (tid & 15) * 4;    // 0..60

    const float* Arow = A + (size_t)(by * 64 + a_r) * K;

    for (int k0 = 0; k0 < K; k0 += 16) {
        float4 av = *(const float4*)&Arow[k0 + a_c4];
        *(float4*)&As[a_r][a_c4] = av;
        float4 bv = *(const float4*)&B[(size_t)(k0 + b_r) * N + bx * 64 + b_c4];
        *(float4*)&Bs[b_r][b_c4] = bv;
        __syncthreads();
#pragma unroll
        for (int kk = 0; kk < 16; ++kk) {
            float a0 = As[ty * 4 + 0][kk];
            float a1 = As[ty * 4 + 1][kk];
            float a2 = As[ty * 4 + 2][kk];
            float a3 = As[ty * 4 + 3][kk];
            float4 b = *(float4*)&Bs[kk][tx * 4];
            acc[0][0] += a0 * b.x; acc[0][1] += a0 * b.y; acc[0][2] += a0 * b.z; acc[0][3] += a0 * b.w;
            acc[1][0] += a1 * b.x; acc[1][1] += a1 * b.y; acc[1][2] += a1 * b.z; acc[1][3] += a1 * b.w;
            acc[2][0] += a2 * b.x; acc[2][1] += a2 * b.y; acc[2][2] += a2 * b.z; acc[2][3] += a2 * b.w;
            acc[3][0] += a3 * b.x; acc[3][1] += a3 * b.y; acc[3][2] += a3 * b.z; acc[3][3] += a3 * b.w;
        }
        __syncthreads();
    }
#pragma unroll
    for (int i = 0; i < 4; ++i) {
        int row = by * 64 + ty * 4 + i;
        float4 o = make_float4(acc[i][0], acc[i][1], acc[i][2], acc[i][3]);
        *(float4*)&C[(size_t)row * N + bx * 64 + tx * 4] = o;
    }
}

// ---------------- agg = h * (1/deg) + bias ----------------
__global__ void k_agg_init(const float* __restrict__ h, const float* __restrict__ dinv,
                           const float* __restrict__ bias, float* __restrict__ agg) {
    int idx = blockIdx.x * 256 + threadIdx.x;   // over N_NODES*64 float4 groups
    int n = idx >> 6;
    int f4 = (idx & 63) * 4;
    if (n >= N_NODES) return;
    float dv = dinv[n];
    float inv = dv * dv;
    float4 hv = *(const float4*)&h[(size_t)n * HID + f4];
    float4 o;
    o.x = hv.x * inv + bias[f4 + 0];
    o.y = hv.y * inv + bias[f4 + 1];
    o.z = hv.z * inv + bias[f4 + 2];
    o.w = hv.w * inv + bias[f4 + 3];
    *(float4*)&agg[(size_t)n * HID + f4] = o;
}

// ---------------- edge scatter: agg[dst] += coef * h[src] ----------------
__global__ void k_scatter(const float* __restrict__ h, const int* __restrict__ src,
                          const int* __restrict__ dst, const float* __restrict__ dinv,
                          float* __restrict__ agg, int E) {
    int idx = blockIdx.x * 256 + threadIdx.x;
    int e = idx >> 6;                // 64 consecutive threads per edge
    int f4 = (idx & 63) * 4;
    if (e >= E) return;
    int s = src[e], d = dst[e];
    float coef = dinv[s] * dinv[d];
    float4 hv = *(const float4*)&h[(size_t)s * HID + f4];
    float* ap = &agg[(size_t)d * HID + f4];
    atomicAdd(ap + 0, coef * hv.x);
    atomicAdd(ap + 1, coef * hv.y);
    atomicAdd(ap + 2, coef * hv.z);
    atomicAdd(ap + 3, coef * hv.w);
}

// ---------------- BN ----------------
__global__ void k_zero_bn(float* bnsum, float* bnsq) {
    bnsum[threadIdx.x] = 0.0f;
    bnsq[threadIdx.x] = 0.0f;
}

__global__ __launch_bounds__(256) void k_bn_stats(const float* __restrict__ x,
                                                  float* bnsum, float* bnsq) {
    int f = threadIdx.x;
    int r0 = blockIdx.x * 32;
    float s = 0.0f, sq = 0.0f;
#pragma unroll 4
    for (int r = 0; r < 32; ++r) {
        float v = x[(size_t)(r0 + r) * HID + f];
        s += v;
        sq += v * v;
    }
    atomicAdd(&bnsum[f], s);
    atomicAdd(&bnsq[f], sq);
}

__global__ void k_bn_apply(float* __restrict__ x, const float* __restrict__ bnsum,
                           const float* __restrict__ bnsq, const float* __restrict__ gamma,
                           const float* __restrict__ beta) {
    int idx = blockIdx.x * 256 + threadIdx.x;   // per element
    if (idx >= N_NODES * HID) return;
    int f = idx & (HID - 1);
    const float invN = 1.0f / (float)N_NODES;
    float mean = bnsum[f] * invN;
    float var = bnsq[f] * invN - mean * mean;
    float v = (x[idx] - mean) * rsqrtf(var + BN_EPS) * gamma[f] + beta[f];
    x[idx] = v > 0.0f ? v : 0.0f;
}

// ---------------- global mean pool ----------------
__global__ __launch_bounds__(256) void k_pool(const float* __restrict__ x,
                                              float* __restrict__ pooled) {
    int g = blockIdx.x;
    int f = threadIdx.x;
    float s = 0.0f;
#pragma unroll 4
    for (int r = 0; r < NPG; ++r)
        s += x[(size_t)(g * NPG + r) * HID + f];
    pooled[g * HID + f] = s * (1.0f / (float)NPG);
}

// ---------------- LSTM cell + FC + log_softmax ----------------
__global__ __launch_bounds__(256) void k_head(const float* __restrict__ pooled,
                                              const float* __restrict__ W_ih,
                                              const float* __restrict__ b_ih,
                                              const float* __restrict__ b_hh,
                                              const float* __restrict__ W_fc,
                                              const float* __restrict__ b_fc,
                                              float* __restrict__ out) {
    __shared__ float p[HID];
    __shared__ float lsum[N_CLASSES][256];
    __shared__ float logits[N_CLASSES];
    int g = blockIdx.x, j = threadIdx.x;
    p[j] = pooled[g * HID + j];
    __syncthreads();

    float gi = 0.f, gf = 0.f, gg = 0.f, go = 0.f;
#pragma unroll 4
    for (int k = 0; k < HID; ++k) {
        float pk = p[k];
        const float* w = &W_ih[(size_t)k * (4 * HID) + j];
        gi += pk * w[0];
        gf += pk * w[HID];
        gg += pk * w[2 * HID];
        go += pk * w[3 * HID];
    }
    gi += b_ih[j] + b_hh[j];
    gf += b_ih[HID + j] + b_hh[HID + j];
    gg += b_ih[2 * HID + j] + b_hh[2 * HID + j];
    go += b_ih[3 * HID + j] + b_hh[3 * HID + j];
    (void)gf;  // c0 == 0: forget gate contributes nothing

    float si = 1.f / (1.f + expf(-gi));
    float so = 1.f / (1.f + expf(-go));
    float c1 = si * tanhf(gg);
    float h1 = so * tanhf(c1);

    out[N_GRAPHS * N_CLASSES + g * HID + j] = h1;                       // h1 block
    out[N_GRAPHS * N_CLASSES + N_GRAPHS * HID + g * HID + j] = c1;      // c1 block

    // logits reduce
#pragma unroll
    for (int c = 0; c < N_CLASSES; ++c)
        lsum[c][j] = h1 * W_fc[j * N_CLASSES + c];
    __syncthreads();
    for (int s = 128; s > 0; s >>= 1) {
        if (j < s) {
#pragma unroll
            for (int c = 0; c < N_CLASSES; ++c)
                lsum[c][j] += lsum[c][j + s];
        }
        __syncthreads();
    }
    if (j < N_CLASSES) logits[j] = lsum[j][0] + b_fc[j];
    __syncthreads();
    if (j < N_CLASSES) {
        float m = fmaxf(fmaxf(logits[0], logits[1]), fmaxf(logits[2], logits[3]));
        float lse = m + logf(expf(logits[0] - m) + expf(logits[1] - m) +
                             expf(logits[2] - m) + expf(logits[3] - m));
        out[g * N_CLASSES + j] = logits[j] - lse;
    }
}

extern "C" void kernel_launch(void* const* d_in, const int* in_sizes, int n_in,
                              void* d_out, int out_size, void* d_ws, size_t ws_size,
                              hipStream_t stream) {
    const float* x    = (const float*)d_in[0];
    const int*   ei   = (const int*)d_in[1];
    const float* W1   = (const float*)d_in[3];
    const float* b1   = (const float*)d_in[4];
    const float* g1   = (const float*)d_in[5];
    const float* be1  = (const float*)d_in[6];
    const float* W2   = (const float*)d_in[7];
    const float* b2   = (const float*)d_in[8];
    const float* g2   = (const float*)d_in[9];
    const float* be2  = (const float*)d_in[10];
    const float* W_ih = (const float*)d_in[11];
    const float* b_ih = (const float*)d_in[13];
    const float* b_hh = (const float*)d_in[14];
    const float* W_fc = (const float*)d_in[15];
    const float* b_fc = (const float*)d_in[16];
    float* out = (float*)d_out;

    int E = in_sizes[1] / 2;
    const int* src = ei;
    const int* dst = ei + E;

    float* ws = (float*)d_ws;
    const size_t MAT = (size_t)N_NODES * HID;   // 8388608
    float* bufA   = ws;
    float* bufB   = bufA + MAT;
    float* deg    = bufB + MAT;
    float* dinv   = deg + N_NODES;
    float* bnsum  = dinv + N_NODES;
    float* bnsq   = bnsum + HID;
    float* pooled = bnsq + HID;

    dim3 blk(256);
    int nodeBlocks = (N_NODES + 255) / 256;
    int edgeBlocks = (E + 255) / 256;
    int elemBlocks = (int)((MAT + 255) / 256);          // per-element
    int vec4Blocks = (int)((MAT / 4 + 255) / 256);      // per-float4
    int scatBlocks = (int)(((size_t)E * 64 + 255) / 256);

    // degree (shared by both layers)
    k_init_deg<<<nodeBlocks, blk, 0, stream>>>(deg);
    k_count_deg<<<edgeBlocks, blk, 0, stream>>>(dst, deg, E);
    k_dinv<<<nodeBlocks, blk, 0, stream>>>(deg, dinv);

    dim3 gemmGrid(HID / 64, N_NODES / 64);

    // ---- layer 1 ----
    k_gemm<<<gemmGrid, blk, 0, stream>>>(x, W1, bufA);
    k_agg_init<<<vec4Blocks, blk, 0, stream>>>(bufA, dinv, b1, bufB);
    k_scatter<<<scatBlocks, blk, 0, stream>>>(bufA, src, dst, dinv, bufB, E);
    k_zero_bn<<<1, blk, 0, stream>>>(bnsum, bnsq);
    k_bn_stats<<<N_NODES / 32, blk, 0, stream>>>(bufB, bnsum, bnsq);
    k_bn_apply<<<elemBlocks, blk, 0, stream>>>(bufB, bnsum, bnsq, g1, be1);

    // ---- layer 2 ----
    k_gemm<<<gemmGrid, blk, 0, stream>>>(bufB, W2, bufA);
    k_agg_init<<<vec4Blocks, blk, 0, stream>>>(bufA, dinv, b2, bufB);
    k_scatter<<<scatBlocks, blk, 0, stream>>>(bufA, src, dst, dinv, bufB, E);
    k_zero_bn<<<1, blk, 0, stream>>>(bnsum, bnsq);
    k_bn_stats<<<N_NODES / 32, blk, 0, stream>>>(bufB, bnsum, bnsq);
    k_bn_apply<<<elemBlocks, blk, 0, stream>>>(bufB, bnsum, bnsq, g2, be2);

    // ---- pool + LSTM + FC + log_softmax ----
    k_pool<<<N_GRAPHS, blk, 0, stream>>>(bufB, pooled);
    k_head<<<N_GRAPHS, blk, 0, stream>>>(pooled, W_ih, b_ih, b_hh, W_fc, b_fc, out);
}

// Round 2
// 518.019 us; speedup vs baseline: 7.3510x; 7.3510x over previous
//
#include <hip/hip_runtime.h>
#include <math.h>

#define N_NODES 32768
#define N_FEAT 256
#define HID 256
#define N_GRAPHS 64
#define NPG 512
#define N_CLASSES 4
#define BN_EPS 1e-5f

// ---------------- degree ----------------
__global__ void k_init_deg(float* deg) {
    int i = blockIdx.x * 256 + threadIdx.x;
    if (i < N_NODES) deg[i] = 1.0f;
}

__global__ void k_count_deg(const int* __restrict__ dst, float* deg, int E) {
    int e = blockIdx.x * 256 + threadIdx.x;
    if (e < E) atomicAdd(&deg[dst[e]], 1.0f);
}

__global__ void k_dinv(const float* __restrict__ deg, float* __restrict__ dinv) {
    int i = blockIdx.x * 256 + threadIdx.x;
    if (i < N_NODES) dinv[i] = rsqrtf(deg[i]);
}

// ---------------- CSR build ----------------
// Single block of 256 threads, each owns 128 consecutive nodes.
__global__ __launch_bounds__(256) void k_scan(const float* __restrict__ deg,
                                              int* __restrict__ row_start,
                                              int* __restrict__ cursor) {
    __shared__ int part[256];
    int t = threadIdx.x;
    int base = t * 128;
    int s = 0;
    for (int i = 0; i < 128; ++i) s += (int)deg[base + i] - 1;
    part[t] = s;
    __syncthreads();
    // inclusive Hillis-Steele scan
    for (int off = 1; off < 256; off <<= 1) {
        int v = (t >= off) ? part[t - off] : 0;
        __syncthreads();
        part[t] += v;
        __syncthreads();
    }
    int run = part[t] - s;   // exclusive prefix for this thread's chunk
    for (int i = 0; i < 128; ++i) {
        int n = base + i;
        row_start[n] = run;
        cursor[n] = run;
        run += (int)deg[n] - 1;
    }
}

__global__ void k_fill(const int* __restrict__ src, const int* __restrict__ dst,
                       int* __restrict__ cursor, int* __restrict__ csr_src, int E) {
    int e = blockIdx.x * 256 + threadIdx.x;
    if (e >= E) return;
    int d = dst[e];
    int pos = atomicAdd(&cursor[d], 1);
    csr_src[pos] = src[e];
}

// ---------------- GEMM: C[M,256] = A[M,256] @ B[256,256], fp32 ----------------
__global__ __launch_bounds__(256) void k_gemm(const float* __restrict__ A,
                                              const float* __restrict__ B,
                                              float* __restrict__ C) {
    __shared__ float As[64][20];
    __shared__ float Bs[16][64];
    const int K = 256, N = 256;
    int tid = threadIdx.x;
    int bx = blockIdx.x;
    int by = blockIdx.y;
    int tx = tid & 15, ty = tid >> 4;

    float acc[4][4] = {};

    int a_r  = tid >> 2;
    int a_c4 = (tid & 3) * 4;
    int b_r  = tid >> 4;
    int b_c4 = (tid & 15) * 4;

    const float* Arow = A + (size_t)(by * 64 + a_r) * K;

    for (int k0 = 0; k0 < K; k0 += 16) {
        float4 av = *(const float4*)&Arow[k0 + a_c4];
        *(float4*)&As[a_r][a_c4] = av;
        float4 bv = *(const float4*)&B[(size_t)(k0 + b_r) * N + bx * 64 + b_c4];
        *(float4*)&Bs[b_r][b_c4] = bv;
        __syncthreads();
#pragma unroll
        for (int kk = 0; kk < 16; ++kk) {
            float a0 = As[ty * 4 + 0][kk];
            float a1 = As[ty * 4 + 1][kk];
            float a2 = As[ty * 4 + 2][kk];
            float a3 = As[ty * 4 + 3][kk];
            float4 b = *(float4*)&Bs[kk][tx * 4];
            acc[0][0] += a0 * b.x; acc[0][1] += a0 * b.y; acc[0][2] += a0 * b.z; acc[0][3] += a0 * b.w;
            acc[1][0] += a1 * b.x; acc[1][1] += a1 * b.y; acc[1][2] += a1 * b.z; acc[1][3] += a1 * b.w;
            acc[2][0] += a2 * b.x; acc[2][1] += a2 * b.y; acc[2][2] += a2 * b.z; acc[2][3] += a2 * b.w;
            acc[3][0] += a3 * b.x; acc[3][1] += a3 * b.y; acc[3][2] += a3 * b.z; acc[3][3] += a3 * b.w;
        }
        __syncthreads();
    }
#pragma unroll
    for (int i = 0; i < 4; ++i) {
        int row = by * 64 + ty * 4 + i;
        float4 o = make_float4(acc[i][0], acc[i][1], acc[i][2], acc[i][3]);
        *(float4*)&C[(size_t)row * N + bx * 64 + tx * 4] = o;
    }
}

// ---------------- CSR aggregate: agg[n] = sum_e coef*h[src] + h[n]/deg + bias ----------------
// One wave (64 lanes) per node; 4 nodes per 256-thread block.
__global__ __launch_bounds__(256) void k_aggregate(const float* __restrict__ h,
                                                   const int* __restrict__ csr_src,
                                                   const int* __restrict__ row_start,
                                                   const float* __restrict__ deg,
                                                   const float* __restrict__ dinv,
                                                   const float* __restrict__ bias,
                                                   float* __restrict__ agg) {
    int wid = threadIdx.x >> 6;
    int lane = threadIdx.x & 63;
    int n = blockIdx.x * 4 + wid;
    int f4 = lane * 4;

    float dv = dinv[n];
    int base = row_start[n];
    int cnt = (int)deg[n] - 1;

    float4 hv = *(const float4*)&h[(size_t)n * HID + f4];
    float inv = dv * dv;
    float4 acc;
    acc.x = hv.x * inv + bias[f4 + 0];
    acc.y = hv.y * inv + bias[f4 + 1];
    acc.z = hv.z * inv + bias[f4 + 2];
    acc.w = hv.w * inv + bias[f4 + 3];

    int j = 0;
    for (; j + 4 <= cnt; j += 4) {
        int s0 = csr_src[base + j + 0];
        int s1 = csr_src[base + j + 1];
        int s2 = csr_src[base + j + 2];
        int s3 = csr_src[base + j + 3];
        float c0 = dinv[s0] * dv;
        float c1 = dinv[s1] * dv;
        float c2 = dinv[s2] * dv;
        float c3 = dinv[s3] * dv;
        float4 h0 = *(const float4*)&h[(size_t)s0 * HID + f4];
        float4 h1 = *(const float4*)&h[(size_t)s1 * HID + f4];
        float4 h2 = *(const float4*)&h[(size_t)s2 * HID + f4];
        float4 h3 = *(const float4*)&h[(size_t)s3 * HID + f4];
        acc.x += c0 * h0.x + c1 * h1.x + c2 * h2.x + c3 * h3.x;
        acc.y += c0 * h0.y + c1 * h1.y + c2 * h2.y + c3 * h3.y;
        acc.z += c0 * h0.z + c1 * h1.z + c2 * h2.z + c3 * h3.z;
        acc.w += c0 * h0.w + c1 * h1.w + c2 * h2.w + c3 * h3.w;
    }
    for (; j < cnt; ++j) {
        int s = csr_src[base + j];
        float c = dinv[s] * dv;
        float4 hs = *(const float4*)&h[(size_t)s * HID + f4];
        acc.x += c * hs.x;
        acc.y += c * hs.y;
        acc.z += c * hs.z;
        acc.w += c * hs.w;
    }
    *(float4*)&agg[(size_t)n * HID + f4] = acc;
}

// ---------------- BN ----------------
__global__ void k_zero_bn(float* bnsum, float* bnsq) {
    bnsum[threadIdx.x] = 0.0f;
    bnsq[threadIdx.x] = 0.0f;
}

__global__ __launch_bounds__(256) void k_bn_stats(const float* __restrict__ x,
                                                  float* bnsum, float* bnsq) {
    int f = threadIdx.x;
    int r0 = blockIdx.x * 32;
    float s = 0.0f, sq = 0.0f;
#pragma unroll 4
    for (int r = 0; r < 32; ++r) {
        float v = x[(size_t)(r0 + r) * HID + f];
        s += v;
        sq += v * v;
    }
    atomicAdd(&bnsum[f], s);
    atomicAdd(&bnsq[f], sq);
}

__global__ void k_bn_apply(float* __restrict__ x, const float* __restrict__ bnsum,
                           const float* __restrict__ bnsq, const float* __restrict__ gamma,
                           const float* __restrict__ beta) {
    int idx = blockIdx.x * 256 + threadIdx.x;
    if (idx >= N_NODES * HID) return;
    int f = idx & (HID - 1);
    const float invN = 1.0f / (float)N_NODES;
    float mean = bnsum[f] * invN;
    float var = bnsq[f] * invN - mean * mean;
    float v = (x[idx] - mean) * rsqrtf(var + BN_EPS) * gamma[f] + beta[f];
    x[idx] = v > 0.0f ? v : 0.0f;
}

// ---------------- global mean pool ----------------
__global__ __launch_bounds__(256) void k_pool(const float* __restrict__ x,
                                              float* __restrict__ pooled) {
    int g = blockIdx.x;
    int f = threadIdx.x;
    float s = 0.0f;
#pragma unroll 4
    for (int r = 0; r < NPG; ++r)
        s += x[(size_t)(g * NPG + r) * HID + f];
    pooled[g * HID + f] = s * (1.0f / (float)NPG);
}

// ---------------- LSTM cell + FC + log_softmax ----------------
__global__ __launch_bounds__(256) void k_head(const float* __restrict__ pooled,
                                              const float* __restrict__ W_ih,
                                              const float* __restrict__ b_ih,
                                              const float* __restrict__ b_hh,
                                              const float* __restrict__ W_fc,
                                              const float* __restrict__ b_fc,
                                              float* __restrict__ out) {
    __shared__ float p[HID];
    __shared__ float lsum[N_CLASSES][256];
    __shared__ float logits[N_CLASSES];
    int g = blockIdx.x, j = threadIdx.x;
    p[j] = pooled[g * HID + j];
    __syncthreads();

    float gi = 0.f, gf = 0.f, gg = 0.f, go = 0.f;
#pragma unroll 4
    for (int k = 0; k < HID; ++k) {
        float pk = p[k];
        const float* w = &W_ih[(size_t)k * (4 * HID) + j];
        gi += pk * w[0];
        gf += pk * w[HID];
        gg += pk * w[2 * HID];
        go += pk * w[3 * HID];
    }
    gi += b_ih[j] + b_hh[j];
    gf += b_ih[HID + j] + b_hh[HID + j];
    gg += b_ih[2 * HID + j] + b_hh[2 * HID + j];
    go += b_ih[3 * HID + j] + b_hh[3 * HID + j];
    (void)gf;  // c0 == 0

    float si = 1.f / (1.f + expf(-gi));
    float so = 1.f / (1.f + expf(-go));
    float c1 = si * tanhf(gg);
    float h1 = so * tanhf(c1);

    out[N_GRAPHS * N_CLASSES + g * HID + j] = h1;
    out[N_GRAPHS * N_CLASSES + N_GRAPHS * HID + g * HID + j] = c1;

#pragma unroll
    for (int c = 0; c < N_CLASSES; ++c)
        lsum[c][j] = h1 * W_fc[j * N_CLASSES + c];
    __syncthreads();
    for (int s = 128; s > 0; s >>= 1) {
        if (j < s) {
#pragma unroll
            for (int c = 0; c < N_CLASSES; ++c)
                lsum[c][j] += lsum[c][j + s];
        }
        __syncthreads();
    }
    if (j < N_CLASSES) logits[j] = lsum[j][0] + b_fc[j];
    __syncthreads();
    if (j < N_CLASSES) {
        float m = fmaxf(fmaxf(logits[0], logits[1]), fmaxf(logits[2], logits[3]));
        float lse = m + logf(expf(logits[0] - m) + expf(logits[1] - m) +
                             expf(logits[2] - m) + expf(logits[3] - m));
        out[g * N_CLASSES + j] = logits[j] - lse;
    }
}

extern "C" void kernel_launch(void* const* d_in, const int* in_sizes, int n_in,
                              void* d_out, int out_size, void* d_ws, size_t ws_size,
                              hipStream_t stream) {
    const float* x    = (const float*)d_in[0];
    const int*   ei   = (const int*)d_in[1];
    const float* W1   = (const float*)d_in[3];
    const float* b1   = (const float*)d_in[4];
    const float* g1   = (const float*)d_in[5];
    const float* be1  = (const float*)d_in[6];
    const float* W2   = (const float*)d_in[7];
    const float* b2   = (const float*)d_in[8];
    const float* g2   = (const float*)d_in[9];
    const float* be2  = (const float*)d_in[10];
    const float* W_ih = (const float*)d_in[11];
    const float* b_ih = (const float*)d_in[13];
    const float* b_hh = (const float*)d_in[14];
    const float* W_fc = (const float*)d_in[15];
    const float* b_fc = (const float*)d_in[16];
    float* out = (float*)d_out;

    int E = in_sizes[1] / 2;
    const int* src = ei;
    const int* dst = ei + E;

    float* ws = (float*)d_ws;
    const size_t MAT = (size_t)N_NODES * HID;   // 8388608
    float* bufA   = ws;
    float* bufB   = bufA + MAT;
    float* deg    = bufB + MAT;
    float* dinv   = deg + N_NODES;
    float* bnsum  = dinv + N_NODES;
    float* bnsq   = bnsum + HID;
    float* pooled = bnsq + HID;
    int*   row_start = (int*)(pooled + N_GRAPHS * HID);
    int*   cursor    = row_start + N_NODES;
    int*   csr_src   = cursor + N_NODES;        // E ints

    dim3 blk(256);
    int nodeBlocks = (N_NODES + 255) / 256;
    int edgeBlocks = (E + 255) / 256;
    int elemBlocks = (int)((MAT + 255) / 256);
    int aggBlocks  = N_NODES / 4;

    // degree + CSR (shared by both layers)
    k_init_deg<<<nodeBlocks, blk, 0, stream>>>(deg);
    k_count_deg<<<edgeBlocks, blk, 0, stream>>>(dst, deg, E);
    k_dinv<<<nodeBlocks, blk, 0, stream>>>(deg, dinv);
    k_scan<<<1, blk, 0, stream>>>(deg, row_start, cursor);
    k_fill<<<edgeBlocks, blk, 0, stream>>>(src, dst, cursor, csr_src, E);

    dim3 gemmGrid(HID / 64, N_NODES / 64);

    // ---- layer 1 ----
    k_gemm<<<gemmGrid, blk, 0, stream>>>(x, W1, bufA);
    k_aggregate<<<aggBlocks, blk, 0, stream>>>(bufA, csr_src, row_start, deg, dinv, b1, bufB);
    k_zero_bn<<<1, blk, 0, stream>>>(bnsum, bnsq);
    k_bn_stats<<<N_NODES / 32, blk, 0, stream>>>(bufB, bnsum, bnsq);
    k_bn_apply<<<elemBlocks, blk, 0, stream>>>(bufB, bnsum, bnsq, g1, be1);

    // ---- layer 2 ----
    k_gemm<<<gemmGrid, blk, 0, stream>>>(bufB, W2, bufA);
    k_aggregate<<<aggBlocks, blk, 0, stream>>>(bufA, csr_src, row_start, deg, dinv, b2, bufB);
    k_zero_bn<<<1, blk, 0, stream>>>(bnsum, bnsq);
    k_bn_stats<<<N_NODES / 32, blk, 0, stream>>>(bufB, bnsum, bnsq);
    k_bn_apply<<<elemBlocks, blk, 0, stream>>>(bufB, bnsum, bnsq, g2, be2);

    // ---- pool + head ----
    k_pool<<<N_GRAPHS, blk, 0, stream>>>(bufB, pooled);
    k_head<<<N_GRAPHS, blk, 0, stream>>>(pooled, W_ih, b_ih, b_hh, W_fc, b_fc, out);
}

// Round 3
// 367.791 us; speedup vs baseline: 10.3536x; 1.4085x over previous
//
#include <hip/hip_runtime.h>
#include <math.h>

#define N_NODES 32768
#define N_FEAT 256
#define HID 256
#define N_GRAPHS 64
#define NPG 512
#define N_CLASSES 4
#define BN_EPS 1e-5f

typedef __attribute__((ext_vector_type(8))) short bf16x8;
typedef __attribute__((ext_vector_type(4))) float f32x4;

__device__ __forceinline__ ushort f2b(float f) {
    union { float f; uint u; } v; v.f = f;
    uint u = v.u;
    return (ushort)((u + 0x7FFFu + ((u >> 16) & 1u)) >> 16);   // RNE
}
__device__ __forceinline__ float bf2f(ushort u) {
    union { uint u; float f; } v; v.u = ((uint)u) << 16;
    return v.f;
}

// ---------------- degree ----------------
__global__ void k_init_deg(float* deg) {
    int i = blockIdx.x * 256 + threadIdx.x;
    if (i < N_NODES) deg[i] = 1.0f;
}

__global__ void k_count_deg(const int* __restrict__ dst, float* deg, int E) {
    int e = blockIdx.x * 256 + threadIdx.x;
    if (e < E) atomicAdd(&deg[dst[e]], 1.0f);
}

__global__ void k_dinv(const float* __restrict__ deg, float* __restrict__ dinv) {
    int i = blockIdx.x * 256 + threadIdx.x;
    if (i < N_NODES) dinv[i] = rsqrtf(deg[i]);
}

// ---------------- CSR build ----------------
__global__ __launch_bounds__(256) void k_scan(const float* __restrict__ deg,
                                              int* __restrict__ row_start,
                                              int* __restrict__ cursor) {
    __shared__ int part[256];
    int t = threadIdx.x;
    int base = t * 128;
    int s = 0;
    for (int i = 0; i < 128; ++i) s += (int)deg[base + i] - 1;
    part[t] = s;
    __syncthreads();
    for (int off = 1; off < 256; off <<= 1) {
        int v = (t >= off) ? part[t - off] : 0;
        __syncthreads();
        part[t] += v;
        __syncthreads();
    }
    int run = part[t] - s;
    for (int i = 0; i < 128; ++i) {
        int n = base + i;
        row_start[n] = run;
        cursor[n] = run;
        run += (int)deg[n] - 1;
    }
}

__global__ void k_fill(const int* __restrict__ src, const int* __restrict__ dst,
                       int* __restrict__ cursor, int* __restrict__ csr_src, int E) {
    int e = blockIdx.x * 256 + threadIdx.x;
    if (e >= E) return;
    int d = dst[e];
    int pos = atomicAdd(&cursor[d], 1);
    csr_src[pos] = src[e];
}

// ---------------- prep: fp32 -> bf16 ----------------
__global__ void k_f2b(const float* __restrict__ in, ushort* __restrict__ out, int n8) {
    int i = blockIdx.x * 256 + threadIdx.x;
    if (i >= n8) return;
    float4 v0 = *(const float4*)(in + (size_t)i * 8);
    float4 v1 = *(const float4*)(in + (size_t)i * 8 + 4);
    uint4 o;
    o.x = (uint)f2b(v0.x) | ((uint)f2b(v0.y) << 16);
    o.y = (uint)f2b(v0.z) | ((uint)f2b(v0.w) << 16);
    o.z = (uint)f2b(v1.x) | ((uint)f2b(v1.y) << 16);
    o.w = (uint)f2b(v1.z) | ((uint)f2b(v1.w) << 16);
    *(uint4*)(out + (size_t)i * 8) = o;
}

// transpose+convert both weight matrices: Wt[n][k] = W[k][n]
__global__ void k_prep_w(const float* __restrict__ W1, const float* __restrict__ W2,
                         ushort* __restrict__ Wt1, ushort* __restrict__ Wt2) {
    int b = blockIdx.x;                       // 0..511
    const float* W = (b < 256) ? W1 : W2;
    ushort* Wt = (b < 256) ? Wt1 : Wt2;
    int n = b & 255;
    int k = threadIdx.x;
    Wt[n * 256 + k] = f2b(W[k * 256 + n]);
}

// ---------------- bf16 MFMA GEMM: C[M,256] = A[M,256] @ Bt^T ----------------
// A row-major bf16 [M,K], Bt col-major bf16 [N,K]. No LDS, no barriers:
// fragments loaded straight from L2/L3 (A panel 16.7MB read 4x, B 128KB).
__global__ __launch_bounds__(256) void k_gemm_bf16(const ushort* __restrict__ A,
                                                   const ushort* __restrict__ Bt,
                                                   ushort* __restrict__ C) {
    int wid = threadIdx.x >> 6;
    int lane = threadIdx.x & 63;
    int m0 = blockIdx.y * 256 + wid * 64;
    int n0 = blockIdx.x * 64;
    int r = lane & 15;           // row (A) / col (B) within fragment
    int ko = (lane >> 4) * 8;    // k offset within 32-slice

    const ushort* Ab = A + (size_t)(m0 + r) * 256 + ko;
    const ushort* Bb = Bt + (size_t)(n0 + r) * 256 + ko;

    f32x4 acc[4][4] = {};
#pragma unroll
    for (int ks = 0; ks < 8; ++ks) {
        bf16x8 a[4], b[4];
#pragma unroll
        for (int i = 0; i < 4; ++i) {
            a[i] = *(const bf16x8*)(Ab + i * (16 * 256) + ks * 32);
            b[i] = *(const bf16x8*)(Bb + i * (16 * 256) + ks * 32);
        }
#pragma unroll
        for (int i = 0; i < 4; ++i)
#pragma unroll
            for (int j = 0; j < 4; ++j)
                acc[i][j] = __builtin_amdgcn_mfma_f32_16x16x32_bf16(a[i], b[j], acc[i][j], 0, 0, 0);
    }

    int rr = (lane >> 4) * 4;   // C/D: row = (lane>>4)*4 + reg, col = lane&15
    int cc = lane & 15;
#pragma unroll
    for (int i = 0; i < 4; ++i) {
        int row = m0 + i * 16 + rr;
#pragma unroll
        for (int j = 0; j < 4; ++j) {
            int col = n0 + j * 16 + cc;
#pragma unroll
            for (int r2 = 0; r2 < 4; ++r2)
                C[(size_t)(row + r2) * 256 + col] = f2b(acc[i][j][r2]);
        }
    }
}

// ---------------- CSR aggregate (bf16 h): agg = sum coef*h[src] + h[n]/deg + bias ----------------
__global__ __launch_bounds__(256) void k_aggregate_b(const ushort* __restrict__ h,
                                                     const int* __restrict__ csr_src,
                                                     const int* __restrict__ row_start,
                                                     const float* __restrict__ deg,
                                                     const float* __restrict__ dinv,
                                                     const float* __restrict__ bias,
                                                     float* __restrict__ agg) {
    int wid = threadIdx.x >> 6;
    int lane = threadIdx.x & 63;
    int n = blockIdx.x * 4 + wid;
    int f4 = lane * 4;

    float dv = dinv[n];
    int base = row_start[n];
    int cnt = (int)deg[n] - 1;

    ushort4 hv = *(const ushort4*)(h + (size_t)n * HID + f4);
    float inv = dv * dv;
    float4 acc;
    acc.x = bf2f(hv.x) * inv + bias[f4 + 0];
    acc.y = bf2f(hv.y) * inv + bias[f4 + 1];
    acc.z = bf2f(hv.z) * inv + bias[f4 + 2];
    acc.w = bf2f(hv.w) * inv + bias[f4 + 3];

    int j = 0;
    for (; j + 4 <= cnt; j += 4) {
        int s0 = csr_src[base + j + 0];
        int s1 = csr_src[base + j + 1];
        int s2 = csr_src[base + j + 2];
        int s3 = csr_src[base + j + 3];
        float c0 = dinv[s0] * dv;
        float c1 = dinv[s1] * dv;
        float c2 = dinv[s2] * dv;
        float c3 = dinv[s3] * dv;
        ushort4 h0 = *(const ushort4*)(h + (size_t)s0 * HID + f4);
        ushort4 h1 = *(const ushort4*)(h + (size_t)s1 * HID + f4);
        ushort4 h2 = *(const ushort4*)(h + (size_t)s2 * HID + f4);
        ushort4 h3 = *(const ushort4*)(h + (size_t)s3 * HID + f4);
        acc.x += c0 * bf2f(h0.x) + c1 * bf2f(h1.x) + c2 * bf2f(h2.x) + c3 * bf2f(h3.x);
        acc.y += c0 * bf2f(h0.y) + c1 * bf2f(h1.y) + c2 * bf2f(h2.y) + c3 * bf2f(h3.y);
        acc.z += c0 * bf2f(h0.z) + c1 * bf2f(h1.z) + c2 * bf2f(h2.z) + c3 * bf2f(h3.z);
        acc.w += c0 * bf2f(h0.w) + c1 * bf2f(h1.w) + c2 * bf2f(h2.w) + c3 * bf2f(h3.w);
    }
    for (; j < cnt; ++j) {
        int s = csr_src[base + j];
        float c = dinv[s] * dv;
        ushort4 hs = *(const ushort4*)(h + (size_t)s * HID + f4);
        acc.x += c * bf2f(hs.x);
        acc.y += c * bf2f(hs.y);
        acc.z += c * bf2f(hs.z);
        acc.w += c * bf2f(hs.w);
    }
    *(float4*)&agg[(size_t)n * HID + f4] = acc;
}

// ---------------- BN ----------------
__global__ void k_zero_bn(float* bnsum, float* bnsq) {
    bnsum[threadIdx.x] = 0.0f;
    bnsq[threadIdx.x] = 0.0f;
}

__global__ __launch_bounds__(256) void k_bn_stats(const float* __restrict__ x,
                                                  float* bnsum, float* bnsq) {
    int f = threadIdx.x;
    int r0 = blockIdx.x * 32;
    float s = 0.0f, sq = 0.0f;
#pragma unroll 4
    for (int r = 0; r < 32; ++r) {
        float v = x[(size_t)(r0 + r) * HID + f];
        s += v;
        sq += v * v;
    }
    atomicAdd(&bnsum[f], s);
    atomicAdd(&bnsq[f], sq);
}

// layer-1 variant: write bf16 (feeds GEMM2)
__global__ void k_bn_apply_b(const float* __restrict__ x, const float* __restrict__ bnsum,
                             const float* __restrict__ bnsq, const float* __restrict__ gamma,
                             const float* __restrict__ beta, ushort* __restrict__ out) {
    int i = blockIdx.x * 256 + threadIdx.x;   // over MAT/4 float4 groups
    if (i >= N_NODES * HID / 4) return;
    int f = (i & 63) * 4;
    const float invN = 1.0f / (float)N_NODES;
    float4 v = *(const float4*)(x + (size_t)i * 4);
    float r[4];
    float vv[4] = {v.x, v.y, v.z, v.w};
#pragma unroll
    for (int q = 0; q < 4; ++q) {
        float mean = bnsum[f + q] * invN;
        float var = bnsq[f + q] * invN - mean * mean;
        float t = (vv[q] - mean) * rsqrtf(var + BN_EPS) * gamma[f + q] + beta[f + q];
        r[q] = t > 0.0f ? t : 0.0f;
    }
    uint2 o;
    o.x = (uint)f2b(r[0]) | ((uint)f2b(r[1]) << 16);
    o.y = (uint)f2b(r[2]) | ((uint)f2b(r[3]) << 16);
    *(uint2*)(out + (size_t)i * 4) = o;
}

// layer-2 variant: in-place fp32 (feeds pool)
__global__ void k_bn_apply(float* __restrict__ x, const float* __restrict__ bnsum,
                           const float* __restrict__ bnsq, const float* __restrict__ gamma,
                           const float* __restrict__ beta) {
    int idx = blockIdx.x * 256 + threadIdx.x;
    if (idx >= N_NODES * HID) return;
    int f = idx & (HID - 1);
    const float invN = 1.0f / (float)N_NODES;
    float mean = bnsum[f] * invN;
    float var = bnsq[f] * invN - mean * mean;
    float v = (x[idx] - mean) * rsqrtf(var + BN_EPS) * gamma[f] + beta[f];
    x[idx] = v > 0.0f ? v : 0.0f;
}

// ---------------- global mean pool ----------------
__global__ __launch_bounds__(256) void k_pool(const float* __restrict__ x,
                                              float* __restrict__ pooled) {
    int g = blockIdx.x;
    int f = threadIdx.x;
    float s = 0.0f;
#pragma unroll 4
    for (int r = 0; r < NPG; ++r)
        s += x[(size_t)(g * NPG + r) * HID + f];
    pooled[g * HID + f] = s * (1.0f / (float)NPG);
}

// ---------------- LSTM cell + FC + log_softmax ----------------
__global__ __launch_bounds__(256) void k_head(const float* __restrict__ pooled,
                                              const float* __restrict__ W_ih,
                                              const float* __restrict__ b_ih,
                                              const float* __restrict__ b_hh,
                                              const float* __restrict__ W_fc,
                                              const float* __restrict__ b_fc,
                                              float* __restrict__ out) {
    __shared__ float p[HID];
    __shared__ float lsum[N_CLASSES][256];
    __shared__ float logits[N_CLASSES];
    int g = blockIdx.x, j = threadIdx.x;
    p[j] = pooled[g * HID + j];
    __syncthreads();

    float gi = 0.f, gf = 0.f, gg = 0.f, go = 0.f;
#pragma unroll 4
    for (int k = 0; k < HID; ++k) {
        float pk = p[k];
        const float* w = &W_ih[(size_t)k * (4 * HID) + j];
        gi += pk * w[0];
        gf += pk * w[HID];
        gg += pk * w[2 * HID];
        go += pk * w[3 * HID];
    }
    gi += b_ih[j] + b_hh[j];
    gf += b_ih[HID + j] + b_hh[HID + j];
    gg += b_ih[2 * HID + j] + b_hh[2 * HID + j];
    go += b_ih[3 * HID + j] + b_hh[3 * HID + j];
    (void)gf;  // c0 == 0

    float si = 1.f / (1.f + expf(-gi));
    float so = 1.f / (1.f + expf(-go));
    float c1 = si * tanhf(gg);
    float h1 = so * tanhf(c1);

    out[N_GRAPHS * N_CLASSES + g * HID + j] = h1;
    out[N_GRAPHS * N_CLASSES + N_GRAPHS * HID + g * HID + j] = c1;

#pragma unroll
    for (int c = 0; c < N_CLASSES; ++c)
        lsum[c][j] = h1 * W_fc[j * N_CLASSES + c];
    __syncthreads();
    for (int s = 128; s > 0; s >>= 1) {
        if (j < s) {
#pragma unroll
            for (int c = 0; c < N_CLASSES; ++c)
                lsum[c][j] += lsum[c][j + s];
        }
        __syncthreads();
    }
    if (j < N_CLASSES) logits[j] = lsum[j][0] + b_fc[j];
    __syncthreads();
    if (j < N_CLASSES) {
        float m = fmaxf(fmaxf(logits[0], logits[1]), fmaxf(logits[2], logits[3]));
        float lse = m + logf(expf(logits[0] - m) + expf(logits[1] - m) +
                             expf(logits[2] - m) + expf(logits[3] - m));
        out[g * N_CLASSES + j] = logits[j] - lse;
    }
}

extern "C" void kernel_launch(void* const* d_in, const int* in_sizes, int n_in,
                              void* d_out, int out_size, void* d_ws, size_t ws_size,
                              hipStream_t stream) {
    const float* x    = (const float*)d_in[0];
    const int*   ei   = (const int*)d_in[1];
    const float* W1   = (const float*)d_in[3];
    const float* b1   = (const float*)d_in[4];
    const float* g1   = (const float*)d_in[5];
    const float* be1  = (const float*)d_in[6];
    const float* W2   = (const float*)d_in[7];
    const float* b2   = (const float*)d_in[8];
    const float* g2   = (const float*)d_in[9];
    const float* be2  = (const float*)d_in[10];
    const float* W_ih = (const float*)d_in[11];
    const float* b_ih = (const float*)d_in[13];
    const float* b_hh = (const float*)d_in[14];
    const float* W_fc = (const float*)d_in[15];
    const float* b_fc = (const float*)d_in[16];
    float* out = (float*)d_out;

    int E = in_sizes[1] / 2;
    const int* src = ei;
    const int* dst = ei + E;

    const size_t MAT = (size_t)N_NODES * HID;   // 8388608
    float*  agg  = (float*)d_ws;
    ushort* xb   = (ushort*)(agg + MAT);        // bf16 GEMM-A buffer (x, then bn1 out)
    ushort* hb   = xb + MAT;                    // bf16 GEMM output
    ushort* Wt1  = hb + MAT;
    ushort* Wt2  = Wt1 + 65536;
    float*  deg  = (float*)(Wt2 + 65536);
    float*  dinv = deg + N_NODES;
    float*  bnsum  = dinv + N_NODES;
    float*  bnsq   = bnsum + HID;
    float*  pooled = bnsq + HID;
    int*    row_start = (int*)(pooled + N_GRAPHS * HID);
    int*    cursor    = row_start + N_NODES;
    int*    csr_src   = cursor + N_NODES;       // E ints

    dim3 blk(256);
    int nodeBlocks = (N_NODES + 255) / 256;
    int edgeBlocks = (E + 255) / 256;
    int elemBlocks = (int)((MAT + 255) / 256);
    int vec4Blocks = (int)((MAT / 4 + 255) / 256);
    int v8Blocks   = (int)((MAT / 8 + 255) / 256);
    int aggBlocks  = N_NODES / 4;
    dim3 gemmGrid(HID / 64, N_NODES / 256);

    // graph structure + weight prep
    k_init_deg<<<nodeBlocks, blk, 0, stream>>>(deg);
    k_count_deg<<<edgeBlocks, blk, 0, stream>>>(dst, deg, E);
    k_dinv<<<nodeBlocks, blk, 0, stream>>>(deg, dinv);
    k_scan<<<1, blk, 0, stream>>>(deg, row_start, cursor);
    k_fill<<<edgeBlocks, blk, 0, stream>>>(src, dst, cursor, csr_src, E);
    k_f2b<<<v8Blocks, blk, 0, stream>>>(x, xb, (int)(MAT / 8));
    k_prep_w<<<512, blk, 0, stream>>>(W1, W2, Wt1, Wt2);

    // ---- layer 1 ----
    k_gemm_bf16<<<gemmGrid, blk, 0, stream>>>(xb, Wt1, hb);
    k_aggregate_b<<<aggBlocks, blk, 0, stream>>>(hb, csr_src, row_start, deg, dinv, b1, agg);
    k_zero_bn<<<1, blk, 0, stream>>>(bnsum, bnsq);
    k_bn_stats<<<N_NODES / 32, blk, 0, stream>>>(agg, bnsum, bnsq);
    k_bn_apply_b<<<vec4Blocks, blk, 0, stream>>>(agg, bnsum, bnsq, g1, be1, xb);

    // ---- layer 2 ----
    k_gemm_bf16<<<gemmGrid, blk, 0, stream>>>(xb, Wt2, hb);
    k_aggregate_b<<<aggBlocks, blk, 0, stream>>>(hb, csr_src, row_start, deg, dinv, b2, agg);
    k_zero_bn<<<1, blk, 0, stream>>>(bnsum, bnsq);
    k_bn_stats<<<N_NODES / 32, blk, 0, stream>>>(agg, bnsum, bnsq);
    k_bn_apply<<<elemBlocks, blk, 0, stream>>>(agg, bnsum, bnsq, g2, be2);

    // ---- pool + head ----
    k_pool<<<N_GRAPHS, blk, 0, stream>>>(agg, pooled);
    k_head<<<N_GRAPHS, blk, 0, stream>>>(pooled, W_ih, b_ih, b_hh, W_fc, b_fc, out);
}

// Round 4
// 352.242 us; speedup vs baseline: 10.8106x; 1.0441x over previous
//
#include <hip/hip_runtime.h>
#include <math.h>

#define N_NODES 32768
#define N_FEAT 256
#define HID 256
#define N_GRAPHS 64
#define NPG 512
#define N_CLASSES 4
#define BN_EPS 1e-5f

typedef __attribute__((ext_vector_type(8))) short bf16x8;
typedef __attribute__((ext_vector_type(4))) float f32x4;

__device__ __forceinline__ ushort f2b(float f) {
    union { float f; uint u; } v; v.f = f;
    uint u = v.u;
    return (ushort)((u + 0x7FFFu + ((u >> 16) & 1u)) >> 16);   // RNE
}
__device__ __forceinline__ float bf2f(ushort u) {
    union { uint u; float f; } v; v.u = ((uint)u) << 16;
    return v.f;
}

// ---------------- degree (int) ----------------
__global__ void k_count(const int* __restrict__ dst, int* __restrict__ degcnt, int E) {
    int e = blockIdx.x * 256 + threadIdx.x;
    if (e < E) atomicAdd(&degcnt[dst[e]], 1);
}

// single block: scan degcnt -> row_start/cursor, dinv = rsqrt(cnt+1)
__global__ __launch_bounds__(256) void k_scan_all(const int* __restrict__ degcnt,
                                                  float* __restrict__ dinv,
                                                  int* __restrict__ row_start,
                                                  int* __restrict__ cursor) {
    __shared__ int part[256];
    int t = threadIdx.x;
    int base = t * 128;
    int s = 0;
    for (int i = 0; i < 128; ++i) s += degcnt[base + i];
    part[t] = s;
    __syncthreads();
    for (int off = 1; off < 256; off <<= 1) {
        int v = (t >= off) ? part[t - off] : 0;
        __syncthreads();
        part[t] += v;
        __syncthreads();
    }
    int run = part[t] - s;
    for (int i = 0; i < 128; ++i) {
        int n = base + i;
        int c = degcnt[n];
        row_start[n] = run;
        cursor[n] = run;
        dinv[n] = rsqrtf((float)(c + 1));
        run += c;
    }
}

__global__ void k_fill(const int* __restrict__ src, const int* __restrict__ dst,
                       int* __restrict__ cursor, int* __restrict__ csr_src, int E) {
    int e = blockIdx.x * 256 + threadIdx.x;
    if (e >= E) return;
    int d = dst[e];
    int pos = atomicAdd(&cursor[d], 1);
    csr_src[pos] = src[e];
}

// ---------------- prep: x->bf16 (blocks 0..n8blk-1) + W transpose (last 512 blocks) ----------------
__global__ void k_prep(const float* __restrict__ x, ushort* __restrict__ xb, int n8blk,
                       const float* __restrict__ W1, const float* __restrict__ W2,
                       ushort* __restrict__ Wt1, ushort* __restrict__ Wt2) {
    int b = blockIdx.x;
    if (b < n8blk) {
        int i = b * 256 + threadIdx.x;
        float4 v0 = *(const float4*)(x + (size_t)i * 8);
        float4 v1 = *(const float4*)(x + (size_t)i * 8 + 4);
        uint4 o;
        o.x = (uint)f2b(v0.x) | ((uint)f2b(v0.y) << 16);
        o.y = (uint)f2b(v0.z) | ((uint)f2b(v0.w) << 16);
        o.z = (uint)f2b(v1.x) | ((uint)f2b(v1.y) << 16);
        o.w = (uint)f2b(v1.z) | ((uint)f2b(v1.w) << 16);
        *(uint4*)(xb + (size_t)i * 8) = o;
    } else {
        int wb = b - n8blk;                   // 0..511
        const float* W = (wb < 256) ? W1 : W2;
        ushort* Wt = (wb < 256) ? Wt1 : Wt2;
        int n = wb & 255;
        int k = threadIdx.x;
        Wt[n * 256 + k] = f2b(W[k * 256 + n]);
    }
}

// ---------------- bf16 MFMA GEMM: hs[slice][row][32] = A[M,256] @ Bt^T ----------------
__global__ __launch_bounds__(256) void k_gemm_bf16(const ushort* __restrict__ A,
                                                   const ushort* __restrict__ Bt,
                                                   ushort* __restrict__ hs) {
    int wid = threadIdx.x >> 6;
    int lane = threadIdx.x & 63;
    int m0 = blockIdx.y * 256 + wid * 64;
    int n0 = blockIdx.x * 64;
    int r = lane & 15;
    int ko = (lane >> 4) * 8;

    const ushort* Ab = A + (size_t)(m0 + r) * 256 + ko;
    const ushort* Bb = Bt + (size_t)(n0 + r) * 256 + ko;

    f32x4 acc[4][4] = {};
#pragma unroll
    for (int ks = 0; ks < 8; ++ks) {
        bf16x8 a[4], b[4];
#pragma unroll
        for (int i = 0; i < 4; ++i) {
            a[i] = *(const bf16x8*)(Ab + i * (16 * 256) + ks * 32);
            b[i] = *(const bf16x8*)(Bb + i * (16 * 256) + ks * 32);
        }
#pragma unroll
        for (int i = 0; i < 4; ++i)
#pragma unroll
            for (int j = 0; j < 4; ++j)
                acc[i][j] = __builtin_amdgcn_mfma_f32_16x16x32_bf16(a[i], b[j], acc[i][j], 0, 0, 0);
    }

    int rr = (lane >> 4) * 4;   // C/D: row=(lane>>4)*4+reg, col=lane&15
    int cc = lane & 15;
#pragma unroll
    for (int i = 0; i < 4; ++i) {
        int row = m0 + i * 16 + rr;
#pragma unroll
        for (int j = 0; j < 4; ++j) {
            int col = n0 + j * 16 + cc;
            int slice = col >> 5;
            int within = col & 31;
            ushort* dstp = hs + (size_t)slice * (N_NODES * 32) + (size_t)row * 32 + within;
#pragma unroll
            for (int r2 = 0; r2 < 4; ++r2)
                dstp[(size_t)r2 * 32] = f2b(acc[i][j][r2]);
        }
    }
}

// ---------------- sliced CSR aggregate + fused BN stats ----------------
// hs[slice][node][32] bf16. blockIdx.x&7 = slice (XCD-pinned via round-robin).
// Block = 4 waves; wave handles 8 nodes sequentially; lane = (edge-subset j4)*16 + feature-pair fp.
__global__ __launch_bounds__(256) void k_agg_bn(const ushort* __restrict__ hs,
                                                const int* __restrict__ csr_src,
                                                const int* __restrict__ row_start,
                                                const int* __restrict__ degcnt,
                                                const float* __restrict__ dinv,
                                                const float* __restrict__ bias,
                                                float* __restrict__ agg,
                                                float* __restrict__ bnsum,
                                                float* __restrict__ bnsq) {
    int slice = blockIdx.x & 7;
    int grp = blockIdx.x >> 3;            // 0..1023
    int wid = threadIdx.x >> 6;
    int lane = threadIdx.x & 63;
    int j4 = lane >> 4;                   // 0..3 edge subset
    int fp = lane & 15;                   // feature pair (2 bf16)
    const ushort* hS = hs + (size_t)slice * (N_NODES * 32);

    float b0 = 0.f, b1v = 0.f;
    if (j4 == 0) {
        b0 = bias[slice * 32 + fp * 2];
        b1v = bias[slice * 32 + fp * 2 + 1];
    }

    float s0 = 0.f, q0 = 0.f, s1 = 0.f, q1 = 0.f;

    for (int t = 0; t < 8; ++t) {
        int n = grp * 32 + wid * 8 + t;
        float dv = dinv[n];
        int base = row_start[n];
        int cnt = degcnt[n];
        float ax = 0.f, ay = 0.f;
        if (j4 == 0) {
            uint hv = *(const uint*)(hS + (size_t)n * 32 + fp * 2);
            float inv = dv * dv;
            ax = bf2f((ushort)hv) * inv + b0;
            ay = bf2f((ushort)(hv >> 16)) * inv + b1v;
        }
        for (int j = j4; j < cnt; j += 4) {
            int s = csr_src[base + j];
            float c = dinv[s] * dv;
            uint hv = *(const uint*)(hS + (size_t)s * 32 + fp * 2);
            ax += c * bf2f((ushort)hv);
            ay += c * bf2f((ushort)(hv >> 16));
        }
        ax += __shfl_xor(ax, 16); ay += __shfl_xor(ay, 16);
        ax += __shfl_xor(ax, 32); ay += __shfl_xor(ay, 32);
        if (j4 == 0) {
            *(float2*)&agg[(size_t)n * HID + slice * 32 + fp * 2] = make_float2(ax, ay);
            s0 += ax; q0 += ax * ax; s1 += ay; q1 += ay * ay;
        }
    }

    __shared__ float ls[4][16][4];
    if (j4 == 0) {
        ls[wid][fp][0] = s0; ls[wid][fp][1] = q0;
        ls[wid][fp][2] = s1; ls[wid][fp][3] = q1;
    }
    __syncthreads();
    if (threadIdx.x < 64) {
        int f = threadIdx.x >> 2, v = threadIdx.x & 3;
        float tsum = ls[0][f][v] + ls[1][f][v] + ls[2][f][v] + ls[3][f][v];
        int feat = slice * 32 + f * 2 + (v >> 1);
        if ((v & 1) == 0) atomicAdd(&bnsum[feat], tsum);
        else              atomicAdd(&bnsq[feat], tsum);
    }
}

// ---------------- BN apply (layer1): agg fp32 -> bf16 xb ----------------
__global__ void k_bn_apply_b(const float* __restrict__ x, const float* __restrict__ bnsum,
                             const float* __restrict__ bnsq, const float* __restrict__ gamma,
                             const float* __restrict__ beta, ushort* __restrict__ out) {
    int i = blockIdx.x * 256 + threadIdx.x;   // float4 groups
    if (i >= N_NODES * HID / 4) return;
    int f = (i & 63) * 4;
    const float invN = 1.0f / (float)N_NODES;
    float4 v = *(const float4*)(x + (size_t)i * 4);
    float r[4];
    float vv[4] = {v.x, v.y, v.z, v.w};
#pragma unroll
    for (int q = 0; q < 4; ++q) {
        float mean = bnsum[f + q] * invN;
        float var = bnsq[f + q] * invN - mean * mean;
        float t = (vv[q] - mean) * rsqrtf(var + BN_EPS) * gamma[f + q] + beta[f + q];
        r[q] = t > 0.0f ? t : 0.0f;
    }
    uint2 o;
    o.x = (uint)f2b(r[0]) | ((uint)f2b(r[1]) << 16);
    o.y = (uint)f2b(r[2]) | ((uint)f2b(r[3]) << 16);
    *(uint2*)(out + (size_t)i * 4) = o;
}

// ---------------- BN apply (layer2) + mean-pool accumulate ----------------
__global__ __launch_bounds__(256) void k_bn_pool(const float* __restrict__ agg,
                                                 const float* __restrict__ bnsum,
                                                 const float* __restrict__ bnsq,
                                                 const float* __restrict__ gamma,
                                                 const float* __restrict__ beta,
                                                 float* __restrict__ pooled) {
    int g = blockIdx.x >> 4;        // graph
    int blk = blockIdx.x & 15;      // 16 blocks/graph, 32 rows each
    int f = threadIdx.x;
    const float invN = 1.0f / (float)N_NODES;
    float mean = bnsum[f] * invN;
    float var = bnsq[f] * invN - mean * mean;
    float sc = rsqrtf(var + BN_EPS) * gamma[f];
    float sh = beta[f] - mean * sc;
    int r0 = g * NPG + blk * 32;
    float s = 0.0f;
#pragma unroll 4
    for (int r = 0; r < 32; ++r) {
        float v = agg[(size_t)(r0 + r) * HID + f] * sc + sh;
        s += v > 0.0f ? v : 0.0f;
    }
    atomicAdd(&pooled[g * HID + f], s);
}

// ---------------- LSTM cell + FC + log_softmax ----------------
__global__ __launch_bounds__(256) void k_head(const float* __restrict__ pooled,
                                              const float* __restrict__ W_ih,
                                              const float* __restrict__ b_ih,
                                              const float* __restrict__ b_hh,
                                              const float* __restrict__ W_fc,
                                              const float* __restrict__ b_fc,
                                              float* __restrict__ out) {
    __shared__ float p[HID];
    __shared__ float lsum[N_CLASSES][256];
    __shared__ float logits[N_CLASSES];
    int g = blockIdx.x, j = threadIdx.x;
    p[j] = pooled[g * HID + j] * (1.0f / (float)NPG);
    __syncthreads();

    float gi = 0.f, gf = 0.f, gg = 0.f, go = 0.f;
#pragma unroll 4
    for (int k = 0; k < HID; ++k) {
        float pk = p[k];
        const float* w = &W_ih[(size_t)k * (4 * HID) + j];
        gi += pk * w[0];
        gf += pk * w[HID];
        gg += pk * w[2 * HID];
        go += pk * w[3 * HID];
    }
    gi += b_ih[j] + b_hh[j];
    gf += b_ih[HID + j] + b_hh[HID + j];
    gg += b_ih[2 * HID + j] + b_hh[2 * HID + j];
    go += b_ih[3 * HID + j] + b_hh[3 * HID + j];
    (void)gf;  // c0 == 0

    float si = 1.f / (1.f + expf(-gi));
    float so = 1.f / (1.f + expf(-go));
    float c1 = si * tanhf(gg);
    float h1 = so * tanhf(c1);

    out[N_GRAPHS * N_CLASSES + g * HID + j] = h1;
    out[N_GRAPHS * N_CLASSES + N_GRAPHS * HID + g * HID + j] = c1;

#pragma unroll
    for (int c = 0; c < N_CLASSES; ++c)
        lsum[c][j] = h1 * W_fc[j * N_CLASSES + c];
    __syncthreads();
    for (int s = 128; s > 0; s >>= 1) {
        if (j < s) {
#pragma unroll
            for (int c = 0; c < N_CLASSES; ++c)
                lsum[c][j] += lsum[c][j + s];
        }
        __syncthreads();
    }
    if (j < N_CLASSES) logits[j] = lsum[j][0] + b_fc[j];
    __syncthreads();
    if (j < N_CLASSES) {
        float m = fmaxf(fmaxf(logits[0], logits[1]), fmaxf(logits[2], logits[3]));
        float lse = m + logf(expf(logits[0] - m) + expf(logits[1] - m) +
                             expf(logits[2] - m) + expf(logits[3] - m));
        out[g * N_CLASSES + j] = logits[j] - lse;
    }
}

extern "C" void kernel_launch(void* const* d_in, const int* in_sizes, int n_in,
                              void* d_out, int out_size, void* d_ws, size_t ws_size,
                              hipStream_t stream) {
    const float* x    = (const float*)d_in[0];
    const int*   ei   = (const int*)d_in[1];
    const float* W1   = (const float*)d_in[3];
    const float* b1   = (const float*)d_in[4];
    const float* g1   = (const float*)d_in[5];
    const float* be1  = (const float*)d_in[6];
    const float* W2   = (const float*)d_in[7];
    const float* b2   = (const float*)d_in[8];
    const float* g2   = (const float*)d_in[9];
    const float* be2  = (const float*)d_in[10];
    const float* W_ih = (const float*)d_in[11];
    const float* b_ih = (const float*)d_in[13];
    const float* b_hh = (const float*)d_in[14];
    const float* W_fc = (const float*)d_in[15];
    const float* b_fc = (const float*)d_in[16];
    float* out = (float*)d_out;

    int E = in_sizes[1] / 2;
    const int* src = ei;
    const int* dst = ei + E;

    const size_t MAT = (size_t)N_NODES * HID;   // 8388608
    float*  agg  = (float*)d_ws;
    ushort* xb   = (ushort*)(agg + MAT);
    ushort* hs   = xb + MAT;                    // slice-major GEMM output
    ushort* Wt1  = hs + MAT;
    ushort* Wt2  = Wt1 + 65536;
    float*  dinv = (float*)(Wt2 + 65536);
    int*    row_start = (int*)(dinv + N_NODES);
    int*    cursor    = row_start + N_NODES;
    int*    csr_src   = cursor + N_NODES;       // E ints
    // zero-init region (one memset): degcnt + bn1sum/bn1sq/bn2sum/bn2sq + pooled
    int*    degcnt = csr_src + E;
    float*  bn1sum = (float*)(degcnt + N_NODES);
    float*  bn1sq  = bn1sum + HID;
    float*  bn2sum = bn1sq + HID;
    float*  bn2sq  = bn2sum + HID;
    float*  pooled = bn2sq + HID;
    size_t zeroBytes = (size_t)N_NODES * 4 + 4 * HID * 4 + (size_t)N_GRAPHS * HID * 4;

    dim3 blk(256);
    int edgeBlocks = (E + 255) / 256;
    int n8blk = (int)(MAT / 8 / 256);           // 4096
    int vec4Blocks = (int)(MAT / 4 / 256);      // 8192
    dim3 gemmGrid(HID / 64, N_NODES / 256);

    hipMemsetAsync(degcnt, 0, zeroBytes, stream);

    // graph structure + prep
    k_count<<<edgeBlocks, blk, 0, stream>>>(dst, degcnt, E);
    k_scan_all<<<1, blk, 0, stream>>>(degcnt, dinv, row_start, cursor);
    k_fill<<<edgeBlocks, blk, 0, stream>>>(src, dst, cursor, csr_src, E);
    k_prep<<<n8blk + 512, blk, 0, stream>>>(x, xb, n8blk, W1, W2, Wt1, Wt2);

    // ---- layer 1 ----
    k_gemm_bf16<<<gemmGrid, blk, 0, stream>>>(xb, Wt1, hs);
    k_agg_bn<<<8192, blk, 0, stream>>>(hs, csr_src, row_start, degcnt, dinv, b1, agg, bn1sum, bn1sq);
    k_bn_apply_b<<<vec4Blocks, blk, 0, stream>>>(agg, bn1sum, bn1sq, g1, be1, xb);

    // ---- layer 2 ----
    k_gemm_bf16<<<gemmGrid, blk, 0, stream>>>(xb, Wt2, hs);
    k_agg_bn<<<8192, blk, 0, stream>>>(hs, csr_src, row_start, degcnt, dinv, b2, agg, bn2sum, bn2sq);
    k_bn_pool<<<N_GRAPHS * 16, blk, 0, stream>>>(agg, bn2sum, bn2sq, g2, be2, pooled);

    // ---- head ----
    k_head<<<N_GRAPHS, blk, 0, stream>>>(pooled, W_ih, b_ih, b_hh, W_fc, b_fc, out);
}

// Round 5
// 343.791 us; speedup vs baseline: 11.0764x; 1.0246x over previous
//
#include <hip/hip_runtime.h>
#include <math.h>

#define N_NODES 32768
#define N_FEAT 256
#define HID 256
#define N_GRAPHS 64
#define NPG 512
#define N_CLASSES 4
#define BN_EPS 1e-5f

typedef __attribute__((ext_vector_type(8))) short bf16x8;
typedef __attribute__((ext_vector_type(4))) float f32x4;

__device__ __forceinline__ ushort f2b(float f) {
    union { float f; uint u; } v; v.f = f;
    uint u = v.u;
    return (ushort)((u + 0x7FFFu + ((u >> 16) & 1u)) >> 16);   // RNE
}
__device__ __forceinline__ float bf2f(ushort u) {
    union { uint u; float f; } v; v.u = ((uint)u) << 16;
    return v.f;
}

// ---------------- degree (int) ----------------
__global__ void k_count(const int* __restrict__ dst, int* __restrict__ degcnt, int E) {
    int e = blockIdx.x * 256 + threadIdx.x;
    if (e < E) atomicAdd(&degcnt[dst[e]], 1);
}

// single block (1024 thr): scan degcnt -> row_start/cursor, dinv = rsqrt(cnt+1)
__global__ __launch_bounds__(1024) void k_scan_all(const int* __restrict__ degcnt,
                                                   float* __restrict__ dinv,
                                                   int* __restrict__ row_start,
                                                   int* __restrict__ cursor) {
    __shared__ int wsum[16];
    int t = threadIdx.x;
    int base = t * 32;
    int s = 0;
#pragma unroll
    for (int i = 0; i < 32; ++i) s += degcnt[base + i];
    int lane = t & 63, w = t >> 6;
    int v = s;
    for (int off = 1; off < 64; off <<= 1) {
        int u = __shfl_up(v, off);
        if (lane >= off) v += u;
    }
    if (lane == 63) wsum[w] = v;
    __syncthreads();
    if (t < 16) {
        int x = wsum[t];
        for (int off = 1; off < 16; off <<= 1) {
            int u = __shfl_up(x, off, 16);
            if (t >= off) x += u;
        }
        wsum[t] = x;
    }
    __syncthreads();
    int run = ((w > 0) ? wsum[w - 1] : 0) + v - s;   // exclusive prefix of this chunk
    for (int i = 0; i < 32; ++i) {
        int n = base + i;
        int c = degcnt[n];
        row_start[n] = run;
        cursor[n] = run;
        dinv[n] = rsqrtf((float)(c + 1));
        run += c;
    }
}

// fill CSR with packed (src, coef)
__global__ void k_fill(const int* __restrict__ src, const int* __restrict__ dst,
                       const float* __restrict__ dinv, int* __restrict__ cursor,
                       uint2* __restrict__ csr, int E) {
    int e = blockIdx.x * 256 + threadIdx.x;
    if (e >= E) return;
    int d = dst[e], s = src[e];
    float coef = dinv[s] * dinv[d];
    int pos = atomicAdd(&cursor[d], 1);
    csr[pos] = make_uint2((uint)s, __float_as_uint(coef));
}

// ---------------- prep: x->bf16 + W transpose ----------------
__global__ void k_prep(const float* __restrict__ x, ushort* __restrict__ xb, int n8blk,
                       const float* __restrict__ W1, const float* __restrict__ W2,
                       ushort* __restrict__ Wt1, ushort* __restrict__ Wt2) {
    int b = blockIdx.x;
    if (b < n8blk) {
        int i = b * 256 + threadIdx.x;
        float4 v0 = *(const float4*)(x + (size_t)i * 8);
        float4 v1 = *(const float4*)(x + (size_t)i * 8 + 4);
        uint4 o;
        o.x = (uint)f2b(v0.x) | ((uint)f2b(v0.y) << 16);
        o.y = (uint)f2b(v0.z) | ((uint)f2b(v0.w) << 16);
        o.z = (uint)f2b(v1.x) | ((uint)f2b(v1.y) << 16);
        o.w = (uint)f2b(v1.z) | ((uint)f2b(v1.w) << 16);
        *(uint4*)(xb + (size_t)i * 8) = o;
    } else {
        int wb = b - n8blk;                   // 0..511
        const float* W = (wb < 256) ? W1 : W2;
        ushort* Wt = (wb < 256) ? Wt1 : Wt2;
        int n = wb & 255;
        int k = threadIdx.x;
        Wt[n * 256 + k] = f2b(W[k * 256 + n]);
    }
}

// ---------------- bf16 MFMA GEMM: hs[slice][row][32] = A[M,256] @ Bt^T ----------------
__global__ __launch_bounds__(256) void k_gemm_bf16(const ushort* __restrict__ A,
                                                   const ushort* __restrict__ Bt,
                                                   ushort* __restrict__ hs) {
    int wid = threadIdx.x >> 6;
    int lane = threadIdx.x & 63;
    int m0 = blockIdx.y * 256 + wid * 64;
    int n0 = blockIdx.x * 64;
    int r = lane & 15;
    int ko = (lane >> 4) * 8;

    const ushort* Ab = A + (size_t)(m0 + r) * 256 + ko;
    const ushort* Bb = Bt + (size_t)(n0 + r) * 256 + ko;

    f32x4 acc[4][4] = {};
#pragma unroll
    for (int ks = 0; ks < 8; ++ks) {
        bf16x8 a[4], b[4];
#pragma unroll
        for (int i = 0; i < 4; ++i) {
            a[i] = *(const bf16x8*)(Ab + i * (16 * 256) + ks * 32);
            b[i] = *(const bf16x8*)(Bb + i * (16 * 256) + ks * 32);
        }
#pragma unroll
        for (int i = 0; i < 4; ++i)
#pragma unroll
            for (int j = 0; j < 4; ++j)
                acc[i][j] = __builtin_amdgcn_mfma_f32_16x16x32_bf16(a[i], b[j], acc[i][j], 0, 0, 0);
    }

    int rr = (lane >> 4) * 4;   // C/D: row=(lane>>4)*4+reg, col=lane&15
    int cc = lane & 15;
#pragma unroll
    for (int i = 0; i < 4; ++i) {
        int row = m0 + i * 16 + rr;
#pragma unroll
        for (int j = 0; j < 4; ++j) {
            int col = n0 + j * 16 + cc;
            int slice = col >> 5;
            int within = col & 31;
            ushort* dstp = hs + (size_t)slice * (N_NODES * 32) + (size_t)row * 32 + within;
#pragma unroll
            for (int r2 = 0; r2 < 4; ++r2)
                dstp[(size_t)r2 * 32] = f2b(acc[i][j][r2]);
        }
    }
}

// ---------------- sliced CSR aggregate + fused BN stats ----------------
// hs[slice][node][32] bf16. blockIdx.x&7 = slice (XCD-pinned via round-robin).
// Block = 4 waves; wave handles 8 nodes; lane = edge-subset(j4)*16 + feature-pair(fp).
__global__ __launch_bounds__(256) void k_agg_bn(const ushort* __restrict__ hs,
                                                const uint2* __restrict__ csr,
                                                const int* __restrict__ row_start,
                                                const int* __restrict__ degcnt,
                                                const float* __restrict__ dinv,
                                                const float* __restrict__ bias,
                                                float* __restrict__ agg,
                                                float* __restrict__ bnsum,
                                                float* __restrict__ bnsq) {
    int slice = blockIdx.x & 7;
    int grp = blockIdx.x >> 3;            // 0..1023
    int wid = threadIdx.x >> 6;
    int lane = threadIdx.x & 63;
    int j4 = lane >> 4;                   // 0..3 edge subset
    int fp = lane & 15;                   // feature pair (2 bf16)
    const ushort* hS = hs + (size_t)slice * (N_NODES * 32);

    float b0 = 0.f, b1v = 0.f;
    if (j4 == 0) {
        b0 = bias[slice * 32 + fp * 2];
        b1v = bias[slice * 32 + fp * 2 + 1];
    }

    float s0 = 0.f, q0 = 0.f, s1 = 0.f, q1 = 0.f;

    for (int t = 0; t < 8; ++t) {
        int n = grp * 32 + wid * 8 + t;
        int base = row_start[n];
        int cnt = degcnt[n];
        float ax = 0.f, ay = 0.f;
        if (j4 == 0) {
            float dv = dinv[n];
            uint hv = *(const uint*)(hS + (size_t)n * 32 + fp * 2);
            float inv = dv * dv;
            ax = bf2f((ushort)hv) * inv + b0;
            ay = bf2f((ushort)(hv >> 16)) * inv + b1v;
        }
        int j = j4;
        for (; j + 4 < cnt; j += 8) {
            uint2 e0 = csr[base + j];
            uint2 e1 = csr[base + j + 4];
            float c0 = __uint_as_float(e0.y);
            float c1 = __uint_as_float(e1.y);
            uint h0 = *(const uint*)(hS + (size_t)e0.x * 32 + fp * 2);
            uint h1 = *(const uint*)(hS + (size_t)e1.x * 32 + fp * 2);
            ax += c0 * bf2f((ushort)h0) + c1 * bf2f((ushort)h1);
            ay += c0 * bf2f((ushort)(h0 >> 16)) + c1 * bf2f((ushort)(h1 >> 16));
        }
        if (j < cnt) {
            uint2 e0 = csr[base + j];
            float c0 = __uint_as_float(e0.y);
            uint h0 = *(const uint*)(hS + (size_t)e0.x * 32 + fp * 2);
            ax += c0 * bf2f((ushort)h0);
            ay += c0 * bf2f((ushort)(h0 >> 16));
        }
        ax += __shfl_xor(ax, 16); ay += __shfl_xor(ay, 16);
        ax += __shfl_xor(ax, 32); ay += __shfl_xor(ay, 32);
        if (j4 == 0) {
            *(float2*)&agg[(size_t)n * HID + slice * 32 + fp * 2] = make_float2(ax, ay);
            s0 += ax; q0 += ax * ax; s1 += ay; q1 += ay * ay;
        }
    }

    __shared__ float ls[4][16][4];
    if (j4 == 0) {
        ls[wid][fp][0] = s0; ls[wid][fp][1] = q0;
        ls[wid][fp][2] = s1; ls[wid][fp][3] = q1;
    }
    __syncthreads();
    if (threadIdx.x < 64) {
        int f = threadIdx.x >> 2, v = threadIdx.x & 3;
        float tsum = ls[0][f][v] + ls[1][f][v] + ls[2][f][v] + ls[3][f][v];
        int feat = slice * 32 + f * 2 + (v >> 1);
        if ((v & 1) == 0) atomicAdd(&bnsum[feat], tsum);
        else              atomicAdd(&bnsq[feat], tsum);
    }
}

// ---------------- BN apply (layer1): agg fp32 -> bf16 xb ----------------
__global__ void k_bn_apply_b(const float* __restrict__ x, const float* __restrict__ bnsum,
                             const float* __restrict__ bnsq, const float* __restrict__ gamma,
                             const float* __restrict__ beta, ushort* __restrict__ out) {
    int i = blockIdx.x * 256 + threadIdx.x;   // float4 groups
    if (i >= N_NODES * HID / 4) return;
    int f = (i & 63) * 4;
    const float invN = 1.0f / (float)N_NODES;
    float4 v = *(const float4*)(x + (size_t)i * 4);
    float r[4];
    float vv[4] = {v.x, v.y, v.z, v.w};
#pragma unroll
    for (int q = 0; q < 4; ++q) {
        float mean = bnsum[f + q] * invN;
        float var = bnsq[f + q] * invN - mean * mean;
        float t = (vv[q] - mean) * rsqrtf(var + BN_EPS) * gamma[f + q] + beta[f + q];
        r[q] = t > 0.0f ? t : 0.0f;
    }
    uint2 o;
    o.x = (uint)f2b(r[0]) | ((uint)f2b(r[1]) << 16);
    o.y = (uint)f2b(r[2]) | ((uint)f2b(r[3]) << 16);
    *(uint2*)(out + (size_t)i * 4) = o;
}

// ---------------- BN apply (layer2) + mean-pool accumulate ----------------
__global__ __launch_bounds__(256) void k_bn_pool(const float* __restrict__ agg,
                                                 const float* __restrict__ bnsum,
                                                 const float* __restrict__ bnsq,
                                                 const float* __restrict__ gamma,
                                                 const float* __restrict__ beta,
                                                 float* __restrict__ pooled) {
    int g = blockIdx.x >> 4;        // graph
    int blk = blockIdx.x & 15;      // 16 blocks/graph, 32 rows each
    int f = threadIdx.x;
    const float invN = 1.0f / (float)N_NODES;
    float mean = bnsum[f] * invN;
    float var = bnsq[f] * invN - mean * mean;
    float sc = rsqrtf(var + BN_EPS) * gamma[f];
    float sh = beta[f] - mean * sc;
    int r0 = g * NPG + blk * 32;
    float s = 0.0f;
#pragma unroll 4
    for (int r = 0; r < 32; ++r) {
        float v = agg[(size_t)(r0 + r) * HID + f] * sc + sh;
        s += v > 0.0f ? v : 0.0f;
    }
    atomicAdd(&pooled[g * HID + f], s);
}

// ---------------- LSTM cell + FC + log_softmax ----------------
__global__ __launch_bounds__(256) void k_head(const float* __restrict__ pooled,
                                              const float* __restrict__ W_ih,
                                              const float* __restrict__ b_ih,
                                              const float* __restrict__ b_hh,
                                              const float* __restrict__ W_fc,
                                              const float* __restrict__ b_fc,
                                              float* __restrict__ out) {
    __shared__ float p[HID];
    __shared__ float lsum[N_CLASSES][256];
    __shared__ float logits[N_CLASSES];
    int g = blockIdx.x, j = threadIdx.x;
    p[j] = pooled[g * HID + j] * (1.0f / (float)NPG);
    __syncthreads();

    float gi = 0.f, gf = 0.f, gg = 0.f, go = 0.f;
#pragma unroll 4
    for (int k = 0; k < HID; ++k) {
        float pk = p[k];
        const float* w = &W_ih[(size_t)k * (4 * HID) + j];
        gi += pk * w[0];
        gf += pk * w[HID];
        gg += pk * w[2 * HID];
        go += pk * w[3 * HID];
    }
    gi += b_ih[j] + b_hh[j];
    gf += b_ih[HID + j] + b_hh[HID + j];
    gg += b_ih[2 * HID + j] + b_hh[2 * HID + j];
    go += b_ih[3 * HID + j] + b_hh[3 * HID + j];
    (void)gf;  // c0 == 0

    float si = 1.f / (1.f + expf(-gi));
    float so = 1.f / (1.f + expf(-go));
    float c1 = si * tanhf(gg);
    float h1 = so * tanhf(c1);

    out[N_GRAPHS * N_CLASSES + g * HID + j] = h1;
    out[N_GRAPHS * N_CLASSES + N_GRAPHS * HID + g * HID + j] = c1;

#pragma unroll
    for (int c = 0; c < N_CLASSES; ++c)
        lsum[c][j] = h1 * W_fc[j * N_CLASSES + c];
    __syncthreads();
    for (int s = 128; s > 0; s >>= 1) {
        if (j < s) {
#pragma unroll
            for (int c = 0; c < N_CLASSES; ++c)
                lsum[c][j] += lsum[c][j + s];
        }
        __syncthreads();
    }
    if (j < N_CLASSES) logits[j] = lsum[j][0] + b_fc[j];
    __syncthreads();
    if (j < N_CLASSES) {
        float m = fmaxf(fmaxf(logits[0], logits[1]), fmaxf(logits[2], logits[3]));
        float lse = m + logf(expf(logits[0] - m) + expf(logits[1] - m) +
                             expf(logits[2] - m) + expf(logits[3] - m));
        out[g * N_CLASSES + j] = logits[j] - lse;
    }
}

extern "C" void kernel_launch(void* const* d_in, const int* in_sizes, int n_in,
                              void* d_out, int out_size, void* d_ws, size_t ws_size,
                              hipStream_t stream) {
    const float* x    = (const float*)d_in[0];
    const int*   ei   = (const int*)d_in[1];
    const float* W1   = (const float*)d_in[3];
    const float* b1   = (const float*)d_in[4];
    const float* g1   = (const float*)d_in[5];
    const float* be1  = (const float*)d_in[6];
    const float* W2   = (const float*)d_in[7];
    const float* b2   = (const float*)d_in[8];
    const float* g2   = (const float*)d_in[9];
    const float* be2  = (const float*)d_in[10];
    const float* W_ih = (const float*)d_in[11];
    const float* b_ih = (const float*)d_in[13];
    const float* b_hh = (const float*)d_in[14];
    const float* W_fc = (const float*)d_in[15];
    const float* b_fc = (const float*)d_in[16];
    float* out = (float*)d_out;

    int E = in_sizes[1] / 2;
    const int* src = ei;
    const int* dst = ei + E;

    const size_t MAT = (size_t)N_NODES * HID;   // 8388608
    float*  agg  = (float*)d_ws;
    ushort* xb   = (ushort*)(agg + MAT);
    ushort* hs   = xb + MAT;                    // slice-major GEMM output
    ushort* Wt1  = hs + MAT;
    ushort* Wt2  = Wt1 + 65536;
    float*  dinv = (float*)(Wt2 + 65536);
    int*    row_start = (int*)(dinv + N_NODES);
    int*    cursor    = row_start + N_NODES;
    uint2*  csr       = (uint2*)(cursor + N_NODES);   // E uint2 (8B-aligned: all prior sizes even)
    // zero-init region (one memset): degcnt + bn sums + pooled
    int*    degcnt = (int*)(csr + E);
    float*  bn1sum = (float*)(degcnt + N_NODES);
    float*  bn1sq  = bn1sum + HID;
    float*  bn2sum = bn1sq + HID;
    float*  bn2sq  = bn2sum + HID;
    float*  pooled = bn2sq + HID;
    size_t zeroBytes = (size_t)N_NODES * 4 + 4 * HID * 4 + (size_t)N_GRAPHS * HID * 4;

    dim3 blk(256);
    int edgeBlocks = (E + 255) / 256;
    int n8blk = (int)(MAT / 8 / 256);           // 4096
    int vec4Blocks = (int)(MAT / 4 / 256);      // 8192
    dim3 gemmGrid(HID / 64, N_NODES / 256);

    hipMemsetAsync(degcnt, 0, zeroBytes, stream);

    // graph structure + prep
    k_count<<<edgeBlocks, blk, 0, stream>>>(dst, degcnt, E);
    k_scan_all<<<1, dim3(1024), 0, stream>>>(degcnt, dinv, row_start, cursor);
    k_fill<<<edgeBlocks, blk, 0, stream>>>(src, dst, dinv, cursor, csr, E);
    k_prep<<<n8blk + 512, blk, 0, stream>>>(x, xb, n8blk, W1, W2, Wt1, Wt2);

    // ---- layer 1 ----
    k_gemm_bf16<<<gemmGrid, blk, 0, stream>>>(xb, Wt1, hs);
    k_agg_bn<<<8192, blk, 0, stream>>>(hs, csr, row_start, degcnt, dinv, b1, agg, bn1sum, bn1sq);
    k_bn_apply_b<<<vec4Blocks, blk, 0, stream>>>(agg, bn1sum, bn1sq, g1, be1, xb);

    // ---- layer 2 ----
    k_gemm_bf16<<<gemmGrid, blk, 0, stream>>>(xb, Wt2, hs);
    k_agg_bn<<<8192, blk, 0, stream>>>(hs, csr, row_start, degcnt, dinv, b2, agg, bn2sum, bn2sq);
    k_bn_pool<<<N_GRAPHS * 16, blk, 0, stream>>>(agg, bn2sum, bn2sq, g2, be2, pooled);

    // ---- head ----
    k_head<<<N_GRAPHS, blk, 0, stream>>>(pooled, W_ih, b_ih, b_hh, W_fc, b_fc, out);
}

// Round 6
// 309.510 us; speedup vs baseline: 12.3032x; 1.1108x over previous
//
#include <hip/hip_runtime.h>
#include <math.h>

#define N_NODES 32768
#define N_FEAT 256
#define HID 256
#define N_GRAPHS 64
#define NPG 512
#define N_CLASSES 4
#define BN_EPS 1e-5f

typedef __attribute__((ext_vector_type(8))) short bf16x8;
typedef __attribute__((ext_vector_type(4))) float f32x4;

__device__ __forceinline__ ushort f2b(float f) {
    union { float f; uint u; } v; v.f = f;
    uint u = v.u;
    return (ushort)((u + 0x7FFFu + ((u >> 16) & 1u)) >> 16);   // RNE
}
__device__ __forceinline__ float bflo(uint u) {
    union { uint u; float f; } v; v.u = u << 16;
    return v.f;
}
__device__ __forceinline__ float bfhi(uint u) {
    union { uint u; float f; } v; v.u = u & 0xFFFF0000u;
    return v.f;
}

// ---------------- degree (int) ----------------
__global__ void k_count(const int* __restrict__ dst, int* __restrict__ degcnt, int E) {
    int e = blockIdx.x * 256 + threadIdx.x;
    if (e < E) atomicAdd(&degcnt[dst[e]], 1);
}

// single block (1024 thr): scan degcnt -> row_start/cursor, dinv = rsqrt(cnt+1)
__global__ __launch_bounds__(1024) void k_scan_all(const int* __restrict__ degcnt,
                                                   float* __restrict__ dinv,
                                                   int* __restrict__ row_start,
                                                   int* __restrict__ cursor) {
    __shared__ int wsum[16];
    int t = threadIdx.x;
    int base = t * 32;
    int s = 0;
#pragma unroll
    for (int i = 0; i < 32; ++i) s += degcnt[base + i];
    int lane = t & 63, w = t >> 6;
    int v = s;
    for (int off = 1; off < 64; off <<= 1) {
        int u = __shfl_up(v, off);
        if (lane >= off) v += u;
    }
    if (lane == 63) wsum[w] = v;
    __syncthreads();
    if (t < 16) {
        int x = wsum[t];
        for (int off = 1; off < 16; off <<= 1) {
            int u = __shfl_up(x, off, 16);
            if (t >= off) x += u;
        }
        wsum[t] = x;
    }
    __syncthreads();
    int run = ((w > 0) ? wsum[w - 1] : 0) + v - s;
    for (int i = 0; i < 32; ++i) {
        int n = base + i;
        int c = degcnt[n];
        row_start[n] = run;
        cursor[n] = run;
        dinv[n] = rsqrtf((float)(c + 1));
        run += c;
    }
}

// fill CSR with src only
__global__ void k_fill(const int* __restrict__ src, const int* __restrict__ dst,
                       int* __restrict__ cursor, uint* __restrict__ csrs, int E) {
    int e = blockIdx.x * 256 + threadIdx.x;
    if (e >= E) return;
    int d = dst[e];
    int pos = atomicAdd(&cursor[d], 1);
    csrs[pos] = (uint)src[e];
}

// ---------------- prep: x->bf16 + W transpose ----------------
__global__ void k_prep(const float* __restrict__ x, ushort* __restrict__ xb, int n8blk,
                       const float* __restrict__ W1, const float* __restrict__ W2,
                       ushort* __restrict__ Wt1, ushort* __restrict__ Wt2) {
    int b = blockIdx.x;
    if (b < n8blk) {
        int i = b * 256 + threadIdx.x;
        float4 v0 = *(const float4*)(x + (size_t)i * 8);
        float4 v1 = *(const float4*)(x + (size_t)i * 8 + 4);
        uint4 o;
        o.x = (uint)f2b(v0.x) | ((uint)f2b(v0.y) << 16);
        o.y = (uint)f2b(v0.z) | ((uint)f2b(v0.w) << 16);
        o.z = (uint)f2b(v1.x) | ((uint)f2b(v1.y) << 16);
        o.w = (uint)f2b(v1.z) | ((uint)f2b(v1.w) << 16);
        *(uint4*)(xb + (size_t)i * 8) = o;
    } else {
        int wb = b - n8blk;
        const float* W = (wb < 256) ? W1 : W2;
        ushort* Wt = (wb < 256) ? Wt1 : Wt2;
        int n = wb & 255;
        int k = threadIdx.x;
        Wt[n * 256 + k] = f2b(W[k * 256 + n]);
    }
}

// ---------------- bf16 MFMA GEMM: hs[slice][row][32] = dinv[row] * (A @ Bt^T) ----------------
__global__ __launch_bounds__(256) void k_gemm_bf16(const ushort* __restrict__ A,
                                                   const ushort* __restrict__ Bt,
                                                   const float* __restrict__ dinv,
                                                   ushort* __restrict__ hs) {
    int wid = threadIdx.x >> 6;
    int lane = threadIdx.x & 63;
    int m0 = blockIdx.y * 256 + wid * 64;
    int n0 = blockIdx.x * 64;
    int r = lane & 15;
    int ko = (lane >> 4) * 8;

    const ushort* Ab = A + (size_t)(m0 + r) * 256 + ko;
    const ushort* Bb = Bt + (size_t)(n0 + r) * 256 + ko;

    f32x4 acc[4][4] = {};
#pragma unroll
    for (int ks = 0; ks < 8; ++ks) {
        bf16x8 a[4], b[4];
#pragma unroll
        for (int i = 0; i < 4; ++i) {
            a[i] = *(const bf16x8*)(Ab + i * (16 * 256) + ks * 32);
            b[i] = *(const bf16x8*)(Bb + i * (16 * 256) + ks * 32);
        }
#pragma unroll
        for (int i = 0; i < 4; ++i)
#pragma unroll
            for (int j = 0; j < 4; ++j)
                acc[i][j] = __builtin_amdgcn_mfma_f32_16x16x32_bf16(a[i], b[j], acc[i][j], 0, 0, 0);
    }

    int rr = (lane >> 4) * 4;   // C/D: row=(lane>>4)*4+reg, col=lane&15
    int cc = lane & 15;
#pragma unroll
    for (int i = 0; i < 4; ++i) {
        int row = m0 + i * 16 + rr;
#pragma unroll
        for (int r2 = 0; r2 < 4; ++r2) {
            float dv = dinv[row + r2];
#pragma unroll
            for (int j = 0; j < 4; ++j) {
                int col = n0 + j * 16 + cc;
                int slice = col >> 5;
                int within = col & 31;
                hs[(size_t)slice * (N_NODES * 32) + (size_t)(row + r2) * 32 + within] =
                    f2b(acc[i][j][r2] * dv);
            }
        }
    }
}

// ---------------- sliced CSR aggregate + fused BN stats ----------------
// hs[slice][node][32] = dinv-prescaled h'. agg[n] = dv*(sum h'[src] + h'[n]) + bias.
// blockIdx.x&7 = slice (XCD-pinned). Block = 4 waves; wave = 8 nodes;
// lane = edge-subset j8 (0..7) * 8 + feature-quad fp (0..7, 4 bf16 each).
__global__ __launch_bounds__(256) void k_agg_bn(const ushort* __restrict__ hs,
                                                const uint* __restrict__ csrs,
                                                const int* __restrict__ row_start,
                                                const int* __restrict__ degcnt,
                                                const float* __restrict__ dinv,
                                                const float* __restrict__ bias,
                                                float* __restrict__ agg,
                                                float* __restrict__ bnsum,
                                                float* __restrict__ bnsq) {
    int slice = blockIdx.x & 7;
    int grp = blockIdx.x >> 3;
    int wid = threadIdx.x >> 6;
    int lane = threadIdx.x & 63;
    int j8 = lane >> 3;                   // 0..7 edge subset
    int fp = lane & 7;                    // feature quad (4 bf16)
    const ushort* hS = hs + (size_t)slice * (N_NODES * 32);

    float b0 = 0.f, b1 = 0.f, b2 = 0.f, b3 = 0.f;
    if (j8 == 0) {
        b0 = bias[slice * 32 + fp * 4 + 0];
        b1 = bias[slice * 32 + fp * 4 + 1];
        b2 = bias[slice * 32 + fp * 4 + 2];
        b3 = bias[slice * 32 + fp * 4 + 3];
    }

    float st[8] = {0.f, 0.f, 0.f, 0.f, 0.f, 0.f, 0.f, 0.f};  // s0,q0,s1,q1,s2,q2,s3,q3

    for (int t = 0; t < 8; ++t) {
        int n = grp * 32 + wid * 8 + t;
        float dv = dinv[n];
        int base = row_start[n];
        int cnt = degcnt[n];
        float a0 = 0.f, a1 = 0.f, a2 = 0.f, a3 = 0.f;
        if (j8 == 0) {
            uint2 hv = *(const uint2*)(hS + (size_t)n * 32 + fp * 4);
            a0 = bflo(hv.x); a1 = bfhi(hv.x);
            a2 = bflo(hv.y); a3 = bfhi(hv.y);
        }
        int j = j8;
        for (; j + 8 < cnt; j += 16) {
            uint s0 = csrs[base + j];
            uint s1 = csrs[base + j + 8];
            uint2 h0 = *(const uint2*)(hS + (size_t)s0 * 32 + fp * 4);
            uint2 h1 = *(const uint2*)(hS + (size_t)s1 * 32 + fp * 4);
            a0 += bflo(h0.x) + bflo(h1.x);
            a1 += bfhi(h0.x) + bfhi(h1.x);
            a2 += bflo(h0.y) + bflo(h1.y);
            a3 += bfhi(h0.y) + bfhi(h1.y);
        }
        if (j < cnt) {
            uint s0 = csrs[base + j];
            uint2 h0 = *(const uint2*)(hS + (size_t)s0 * 32 + fp * 4);
            a0 += bflo(h0.x); a1 += bfhi(h0.x);
            a2 += bflo(h0.y); a3 += bfhi(h0.y);
        }
        a0 += __shfl_xor(a0, 8);  a1 += __shfl_xor(a1, 8);
        a2 += __shfl_xor(a2, 8);  a3 += __shfl_xor(a3, 8);
        a0 += __shfl_xor(a0, 16); a1 += __shfl_xor(a1, 16);
        a2 += __shfl_xor(a2, 16); a3 += __shfl_xor(a3, 16);
        a0 += __shfl_xor(a0, 32); a1 += __shfl_xor(a1, 32);
        a2 += __shfl_xor(a2, 32); a3 += __shfl_xor(a3, 32);
        if (j8 == 0) {
            float o0 = a0 * dv + b0;
            float o1 = a1 * dv + b1;
            float o2 = a2 * dv + b2;
            float o3 = a3 * dv + b3;
            *(float4*)&agg[(size_t)n * HID + slice * 32 + fp * 4] = make_float4(o0, o1, o2, o3);
            st[0] += o0; st[1] += o0 * o0;
            st[2] += o1; st[3] += o1 * o1;
            st[4] += o2; st[5] += o2 * o2;
            st[6] += o3; st[7] += o3 * o3;
        }
    }

    __shared__ float ls[4][8][8];
    if (j8 == 0) {
#pragma unroll
        for (int v = 0; v < 8; ++v) ls[wid][fp][v] = st[v];
    }
    __syncthreads();
    if (threadIdx.x < 64) {
        int f = threadIdx.x >> 3, v = threadIdx.x & 7;
        float tsum = ls[0][f][v] + ls[1][f][v] + ls[2][f][v] + ls[3][f][v];
        int feat = slice * 32 + f * 4 + (v >> 1);
        if ((v & 1) == 0) atomicAdd(&bnsum[feat], tsum);
        else              atomicAdd(&bnsq[feat], tsum);
    }
}

// ---------------- BN apply (layer1): agg fp32 -> bf16 xb ----------------
__global__ void k_bn_apply_b(const float* __restrict__ x, const float* __restrict__ bnsum,
                             const float* __restrict__ bnsq, const float* __restrict__ gamma,
                             const float* __restrict__ beta, ushort* __restrict__ out) {
    int i = blockIdx.x * 256 + threadIdx.x;
    if (i >= N_NODES * HID / 4) return;
    int f = (i & 63) * 4;
    const float invN = 1.0f / (float)N_NODES;
    float4 v = *(const float4*)(x + (size_t)i * 4);
    float r[4];
    float vv[4] = {v.x, v.y, v.z, v.w};
#pragma unroll
    for (int q = 0; q < 4; ++q) {
        float mean = bnsum[f + q] * invN;
        float var = bnsq[f + q] * invN - mean * mean;
        float t = (vv[q] - mean) * rsqrtf(var + BN_EPS) * gamma[f + q] + beta[f + q];
        r[q] = t > 0.0f ? t : 0.0f;
    }
    uint2 o;
    o.x = (uint)f2b(r[0]) | ((uint)f2b(r[1]) << 16);
    o.y = (uint)f2b(r[2]) | ((uint)f2b(r[3]) << 16);
    *(uint2*)(out + (size_t)i * 4) = o;
}

// ---------------- BN apply (layer2) + mean-pool accumulate ----------------
__global__ __launch_bounds__(256) void k_bn_pool(const float* __restrict__ agg,
                                                 const float* __restrict__ bnsum,
                                                 const float* __restrict__ bnsq,
                                                 const float* __restrict__ gamma,
                                                 const float* __restrict__ beta,
                                                 float* __restrict__ pooled) {
    int g = blockIdx.x >> 4;
    int blk = blockIdx.x & 15;
    int f = threadIdx.x;
    const float invN = 1.0f / (float)N_NODES;
    float mean = bnsum[f] * invN;
    float var = bnsq[f] * invN - mean * mean;
    float sc = rsqrtf(var + BN_EPS) * gamma[f];
    float sh = beta[f] - mean * sc;
    int r0 = g * NPG + blk * 32;
    float s = 0.0f;
#pragma unroll 4
    for (int r = 0; r < 32; ++r) {
        float v = agg[(size_t)(r0 + r) * HID + f] * sc + sh;
        s += v > 0.0f ? v : 0.0f;
    }
    atomicAdd(&pooled[g * HID + f], s);
}

// ---------------- LSTM cell + FC + log_softmax ----------------
__global__ __launch_bounds__(256) void k_head(const float* __restrict__ pooled,
                                              const float* __restrict__ W_ih,
                                              const float* __restrict__ b_ih,
                                              const float* __restrict__ b_hh,
                                              const float* __restrict__ W_fc,
                                              const float* __restrict__ b_fc,
                                              float* __restrict__ out) {
    __shared__ float p[HID];
    __shared__ float lsum[N_CLASSES][256];
    __shared__ float logits[N_CLASSES];
    int g = blockIdx.x, j = threadIdx.x;
    p[j] = pooled[g * HID + j] * (1.0f / (float)NPG);
    __syncthreads();

    float gi = 0.f, gf = 0.f, gg = 0.f, go = 0.f;
#pragma unroll 4
    for (int k = 0; k < HID; ++k) {
        float pk = p[k];
        const float* w = &W_ih[(size_t)k * (4 * HID) + j];
        gi += pk * w[0];
        gf += pk * w[HID];
        gg += pk * w[2 * HID];
        go += pk * w[3 * HID];
    }
    gi += b_ih[j] + b_hh[j];
    gf += b_ih[HID + j] + b_hh[HID + j];
    gg += b_ih[2 * HID + j] + b_hh[2 * HID + j];
    go += b_ih[3 * HID + j] + b_hh[3 * HID + j];
    (void)gf;  // c0 == 0

    float si = 1.f / (1.f + expf(-gi));
    float so = 1.f / (1.f + expf(-go));
    float c1 = si * tanhf(gg);
    float h1 = so * tanhf(c1);

    out[N_GRAPHS * N_CLASSES + g * HID + j] = h1;
    out[N_GRAPHS * N_CLASSES + N_GRAPHS * HID + g * HID + j] = c1;

#pragma unroll
    for (int c = 0; c < N_CLASSES; ++c)
        lsum[c][j] = h1 * W_fc[j * N_CLASSES + c];
    __syncthreads();
    for (int s = 128; s > 0; s >>= 1) {
        if (j < s) {
#pragma unroll
            for (int c = 0; c < N_CLASSES; ++c)
                lsum[c][j] += lsum[c][j + s];
        }
        __syncthreads();
    }
    if (j < N_CLASSES) logits[j] = lsum[j][0] + b_fc[j];
    __syncthreads();
    if (j < N_CLASSES) {
        float m = fmaxf(fmaxf(logits[0], logits[1]), fmaxf(logits[2], logits[3]));
        float lse = m + logf(expf(logits[0] - m) + expf(logits[1] - m) +
                             expf(logits[2] - m) + expf(logits[3] - m));
        out[g * N_CLASSES + j] = logits[j] - lse;
    }
}

extern "C" void kernel_launch(void* const* d_in, const int* in_sizes, int n_in,
                              void* d_out, int out_size, void* d_ws, size_t ws_size,
                              hipStream_t stream) {
    const float* x    = (const float*)d_in[0];
    const int*   ei   = (const int*)d_in[1];
    const float* W1   = (const float*)d_in[3];
    const float* b1   = (const float*)d_in[4];
    const float* g1   = (const float*)d_in[5];
    const float* be1  = (const float*)d_in[6];
    const float* W2   = (const float*)d_in[7];
    const float* b2   = (const float*)d_in[8];
    const float* g2   = (const float*)d_in[9];
    const float* be2  = (const float*)d_in[10];
    const float* W_ih = (const float*)d_in[11];
    const float* b_ih = (const float*)d_in[13];
    const float* b_hh = (const float*)d_in[14];
    const float* W_fc = (const float*)d_in[15];
    const float* b_fc = (const float*)d_in[16];
    float* out = (float*)d_out;

    int E = in_sizes[1] / 2;
    const int* src = ei;
    const int* dst = ei + E;

    const size_t MAT = (size_t)N_NODES * HID;   // 8388608
    float*  agg  = (float*)d_ws;
    ushort* xb   = (ushort*)(agg + MAT);
    ushort* hs   = xb + MAT;                    // slice-major prescaled GEMM output
    ushort* Wt1  = hs + MAT;
    ushort* Wt2  = Wt1 + 65536;
    float*  dinv = (float*)(Wt2 + 65536);
    int*    row_start = (int*)(dinv + N_NODES);
    int*    cursor    = row_start + N_NODES;
    uint*   csrs      = (uint*)(cursor + N_NODES);    // E uints
    // zero-init region (one memset): degcnt + bn sums + pooled
    int*    degcnt = (int*)(csrs + E);
    float*  bn1sum = (float*)(degcnt + N_NODES);
    float*  bn1sq  = bn1sum + HID;
    float*  bn2sum = bn1sq + HID;
    float*  bn2sq  = bn2sum + HID;
    float*  pooled = bn2sq + HID;
    size_t zeroBytes = (size_t)N_NODES * 4 + 4 * HID * 4 + (size_t)N_GRAPHS * HID * 4;

    dim3 blk(256);
    int edgeBlocks = (E + 255) / 256;
    int n8blk = (int)(MAT / 8 / 256);           // 4096
    int vec4Blocks = (int)(MAT / 4 / 256);      // 8192
    dim3 gemmGrid(HID / 64, N_NODES / 256);

    hipMemsetAsync(degcnt, 0, zeroBytes, stream);

    // graph structure + prep
    k_count<<<edgeBlocks, blk, 0, stream>>>(dst, degcnt, E);
    k_scan_all<<<1, dim3(1024), 0, stream>>>(degcnt, dinv, row_start, cursor);
    k_fill<<<edgeBlocks, blk, 0, stream>>>(src, dst, cursor, csrs, E);
    k_prep<<<n8blk + 512, blk, 0, stream>>>(x, xb, n8blk, W1, W2, Wt1, Wt2);

    // ---- layer 1 ----
    k_gemm_bf16<<<gemmGrid, blk, 0, stream>>>(xb, Wt1, dinv, hs);
    k_agg_bn<<<8192, blk, 0, stream>>>(hs, csrs, row_start, degcnt, dinv, b1, agg, bn1sum, bn1sq);
    k_bn_apply_b<<<vec4Blocks, blk, 0, stream>>>(agg, bn1sum, bn1sq, g1, be1, xb);

    // ---- layer 2 ----
    k_gemm_bf16<<<gemmGrid, blk, 0, stream>>>(xb, Wt2, dinv, hs);
    k_agg_bn<<<8192, blk, 0, stream>>>(hs, csrs, row_start, degcnt, dinv, b2, agg, bn2sum, bn2sq);
    k_bn_pool<<<N_GRAPHS * 16, blk, 0, stream>>>(agg, bn2sum, bn2sq, g2, be2, pooled);

    // ---- head ----
    k_head<<<N_GRAPHS, blk, 0, stream>>>(pooled, W_ih, b_ih, b_hh, W_fc, b_fc, out);
}